// Round 3
// baseline (6103.618 us; speedup 1.0000x reference)
//
#include <hip/hip_runtime.h>

// ---------------- workspace layout (floats) ----------------
constexpr size_t OFF_XN  = 0;                      // 512*1024
constexpr size_t OFF_PF  = 524288;                 // 32768*128
constexpr size_t OFF_W2A = OFF_PF  + 4194304;      // 128*128*3  transposed [(cc*3+k)*128+d]
constexpr size_t OFF_W1B = OFF_W2A + 49152;
constexpr size_t OFF_W2B = OFF_W1B + 49152;
constexpr size_t OFF_PW  = OFF_W2B + 49152;        // [(c*16+k)*128+d]
constexpr size_t OFF_UPW = OFF_PW  + 262144;       // [(j*128+e)*128+d]
constexpr size_t OFF_W1D = OFF_UPW + 262144;       // [(c*3+k)*64+o]
constexpr size_t OFF_EMT = OFF_W1D + 24576;        // [j*128+d]
constexpr size_t OFF_EN  = OFF_EMT + 131072;       // 1024
constexpr size_t OFF_RP  = OFF_EN  + 1024;         // 8192 recon partials
constexpr size_t OFF_VP  = OFF_RP  + 8192;         // 4096 vq partials
constexpr size_t OFF_IND = OFF_VP  + 4096;         // 32768 int
// total ~21.6 MB

#define DI __device__ __forceinline__

constexpr int SW = 42;   // encoder LDS row stride (even; 2*SW mod 32 = 20 -> 8-way writes max)

// ---------------- prep: weight transposes + embedT + |e|^2 ----------------
__global__ __launch_bounds__(256) void k_prep(
    const float* __restrict__ w2a, const float* __restrict__ w1b, const float* __restrict__ w2b,
    const float* __restrict__ pw,  const float* __restrict__ upw, const float* __restrict__ w1d,
    const float* __restrict__ em,  float* __restrict__ ws)
{
  int tid = blockIdx.x * 256 + threadIdx.x;
  int stride = gridDim.x * 256;
  for (int i = tid; i < 128*128*3; i += stride) {
    int d = i / 384, r = i % 384;          // r = cc*3+k
    ws[OFF_W2A + (size_t)r*128 + d] = w2a[i];
    ws[OFF_W1B + (size_t)r*128 + d] = w1b[i];
    ws[OFF_W2B + (size_t)r*128 + d] = w2b[i];
  }
  for (int i = tid; i < 128*128*16; i += stride) {
    int d = i / 2048, r = i % 2048;        // r = c*16+k
    ws[OFF_PW + (size_t)r*128 + d] = pw[i];
  }
  for (int i = tid; i < 128*128*16; i += stride) {
    int e = i / 2048, rem = i % 2048;
    int d = rem / 16, j = rem % 16;
    ws[OFF_UPW + (size_t)(j*128 + e)*128 + d] = upw[i];
  }
  for (int i = tid; i < 64*128*3; i += stride) {
    int o = i / 384, r = i % 384;          // r = c*3+k
    ws[OFF_W1D + (size_t)r*64 + o] = w1d[i];
  }
  for (int j = tid; j < 1024; j += stride) {
    float s = 0.f;
    for (int d = 0; d < 128; ++d) {
      float v = em[d*1024 + j];
      ws[OFF_EMT + (size_t)j*128 + d] = v;
      s = fmaf(v, v, s);
    }
    ws[OFF_EN + j] = s;
  }
}

// ---------------- RevIN ----------------
__global__ __launch_bounds__(256) void k_revin(
    const float* __restrict__ x, const float* __restrict__ rw, const float* __restrict__ rb,
    float* __restrict__ xn)
{
  int n = blockIdx.x;            // sample = b*8 + c
  int b = n >> 3, c = n & 7;
  int t = threadIdx.x;
  const float* xp = x + (size_t)b*8192 + c;
  float v[4]; float s = 0.f, s2 = 0.f;
  #pragma unroll
  for (int i = 0; i < 4; ++i) {
    v[i] = xp[(size_t)(t + i*256)*8];
    s += v[i]; s2 = fmaf(v[i], v[i], s2);
  }
  __shared__ float sh[8];
  __shared__ float st[2];
  for (int o = 32; o; o >>= 1) { s += __shfl_down(s, o, 64); s2 += __shfl_down(s2, o, 64); }
  if ((t & 63) == 0) { sh[t >> 6] = s; sh[4 + (t >> 6)] = s2; }
  __syncthreads();
  if (t == 0) {
    float S = sh[0]+sh[1]+sh[2]+sh[3];
    float S2 = sh[4]+sh[5]+sh[6]+sh[7];
    float mu = S * (1.f/1024.f);
    float var = S2 * (1.f/1024.f) - mu*mu;
    st[0] = mu;
    st[1] = 1.f / sqrtf(var + 1e-5f);
  }
  __syncthreads();
  float mu = st[0], inv = st[1], w0 = rw[0], b0 = rb[0];
  #pragma unroll
  for (int i = 0; i < 4; ++i)
    xn[(size_t)n*1024 + t + i*256] = fmaf((v[i]-mu)*inv, w0, b0);
}

// ---------------- conv core: full 128-cc sum, 2 d's, NI cols ----------------
// LDS reads are wave-uniform (addr independent of lane) -> broadcasts, conflict-free.
template<int NI>
DI void convNI(const float* __restrict__ wT, int d0, const float* src, int colb,
               float* a0, float* a1)
{
  for (int cc = 0; cc < 128; ++cc) {
    const float* row = src + cc*SW + colb;
    float r[NI+2];
    #pragma unroll
    for (int x = 0; x < NI+2; x += 2) {
      float2 v = *(const float2*)(row + x);
      r[x] = v.x; r[x+1] = v.y;
    }
    const float* wp = wT + (size_t)cc*384 + d0;
    float2 w0 = *(const float2*)(wp);
    float2 w1 = *(const float2*)(wp + 128);
    float2 w2 = *(const float2*)(wp + 256);
    #pragma unroll
    for (int i = 0; i < NI; ++i) {
      a0[i] = fmaf(w0.x, r[i], fmaf(w1.x, r[i+1], fmaf(w2.x, r[i+2], a0[i])));
      a1[i] = fmaf(w0.y, r[i], fmaf(w1.y, r[i+1], fmaf(w2.y, r[i+2], a1[i])));
    }
  }
}

// ---------------- fused TCN encoder (block0+block1) + patchify GEMM ----------------
// block = (n [0..511], tile [0..31]); covers l in [l0, l0+32) = 2 patches.
// 512 threads: dp = t&63 (d-pair), g = t>>6 (col-group / c-group). LDS 43.2 KB.
__global__ __launch_bounds__(512) void k_encoder(
    float* ws,
    const float* __restrict__ w1a, const float* __restrict__ b1a,
    const float* __restrict__ b2a, const float* __restrict__ wdw, const float* __restrict__ bdw,
    const float* __restrict__ b1b, const float* __restrict__ b2b,
    const float* __restrict__ pb)
{
  __shared__ __align__(16) float xs[48];
  __shared__ __align__(16) float buf1[128*SW];  // h1a -> h1b -> out1
  __shared__ __align__(16) float s0  [128*SW];  // out0 -> GEMM scratch

  const float* xn   = ws + OFF_XN;
  const float* w2aT = ws + OFF_W2A;
  const float* w1bT = ws + OFF_W1B;
  const float* w2bT = ws + OFF_W2B;
  const float* pwT  = ws + OFF_PW;
  float* pf = ws + OFF_PF;

  int blk = blockIdx.x;
  int n = blk >> 5;
  int tile = blk & 31;
  int l0 = tile * 32;
  int t = threadIdx.x;

  if (t < 40) {
    int gl = l0 - 8 + t;
    xs[t] = (gl >= 0 && gl < 1024) ? xn[(size_t)n*1024 + gl] : 0.f;
  }
  __syncthreads();

  // phase 1: h1a cols 0..37, l = l0-6+i  (causal pad -> exact 0)
  {
    int c = t & 127, seg = t >> 7;
    float w0 = w1a[c*3+0], w1 = w1a[c*3+1], w2 = w1a[c*3+2], bb = b1a[c];
    #pragma unroll
    for (int ii = 0; ii < 10; ++ii) {
      int i = seg*10 + ii;
      if (i < 38) {
        float v = fmaf(w0, xs[i], fmaf(w1, xs[i+1], fmaf(w2, xs[i+2], bb)));
        buf1[c*SW + i] = (l0 - 6 + i >= 0) ? fmaxf(v, 0.f) : 0.f;
      }
    }
  }
  __syncthreads();

  int dp = t & 63, d0 = dp*2, g = t >> 6;   // g in 0..7

  // phase 2: out0 cols 0..35, l = l0-4+col. h2=relu(conv(h1a)+b2a); out0=relu(h2+wd*x+bd)
  {
    float a0[6], a1[6];
    float bi0 = b2a[d0], bi1 = b2a[d0+1];
    #pragma unroll
    for (int i = 0; i < 6; ++i) { a0[i] = bi0; a1[i] = bi1; }
    int colb, ni;
    if (g < 2) { colb = 6*g;     convNI<6>(w2aT, d0, buf1, colb, a0, a1); ni = 6; }
    else       { colb = 4*g + 4; convNI<4>(w2aT, d0, buf1, colb, a0, a1); ni = 4; }
    float wv0 = wdw[d0], wv1 = wdw[d0+1], c0 = bdw[d0], c1 = bdw[d0+1];
    for (int i = 0; i < ni; ++i) {
      int col = colb + i;
      bool valid = (l0 - 4 + col >= 0);
      float xv = xs[col + 4];
      float o0 = fmaxf(fmaxf(a0[i], 0.f) + fmaf(wv0, xv, c0), 0.f);
      float o1 = fmaxf(fmaxf(a1[i], 0.f) + fmaf(wv1, xv, c1), 0.f);
      s0[d0*SW + col]     = valid ? o0 : 0.f;
      s0[(d0+1)*SW + col] = valid ? o1 : 0.f;
    }
  }
  __syncthreads();

  // phase 3: h1b cols 0..33, l = l0-2+col (overwrites h1a)
  {
    float a0[6], a1[6];
    float bi0 = b1b[d0], bi1 = b1b[d0+1];
    #pragma unroll
    for (int i = 0; i < 6; ++i) { a0[i] = bi0; a1[i] = bi1; }
    int colb, ni;
    if (g == 0) { colb = 0;       convNI<6>(w1bT, d0, s0, colb, a0, a1); ni = 6; }
    else        { colb = 4*g + 2; convNI<4>(w1bT, d0, s0, colb, a0, a1); ni = 4; }
    for (int i = 0; i < ni; ++i) {
      int col = colb + i;
      bool valid = (l0 - 2 + col >= 0);
      buf1[d0*SW + col]     = valid ? fmaxf(a0[i], 0.f) : 0.f;
      buf1[(d0+1)*SW + col] = valid ? fmaxf(a1[i], 0.f) : 0.f;
    }
  }
  __syncthreads();

  // phase 4: out1 cols 0..31, l = l0+col. out1 = relu(relu(conv(h1b)+b2b) + out0)
  {
    float a0[4], a1[4];
    float bi0 = b2b[d0], bi1 = b2b[d0+1];
    #pragma unroll
    for (int i = 0; i < 4; ++i) { a0[i] = bi0; a1[i] = bi1; }
    int colb = 4*g;
    convNI<4>(w2bT, d0, buf1, colb, a0, a1);
    float o0[4], o1[4];
    #pragma unroll
    for (int i = 0; i < 4; ++i) {
      int col = colb + i;
      o0[i] = fmaxf(fmaxf(a0[i], 0.f) + s0[d0*SW + col + 4], 0.f);
      o1[i] = fmaxf(fmaxf(a1[i], 0.f) + s0[(d0+1)*SW + col + 4], 0.f);
    }
    __syncthreads();           // all h1b reads complete
    #pragma unroll
    for (int i = 0; i < 4; ++i) {
      buf1[d0*SW + colb + i]     = o0[i];   // out1[c][col]
      buf1[(d0+1)*SW + colb + i] = o1[i];
    }
  }
  __syncthreads();

  // patchify: pf[n*64 + tile*2 + p][d] = pb[d] + sum_{c,k} out1[c][16p+k]*pwT[(c*16+k)*128+d]
  // thread: d-pair dp, c-group g covers c in [16g, 16g+16)
  {
    float acc[2][2] = {};
    for (int cl = 0; cl < 16; ++cl) {
      int c = g*16 + cl;
      const float* arow = buf1 + c*SW;
      const float* wrow = pwT + (size_t)c*16*128 + d0;
      for (int k = 0; k < 16; ++k) {
        float2 w = *(const float2*)(wrow + k*128);
        #pragma unroll
        for (int p = 0; p < 2; ++p) {
          float a = arow[p*16 + k];
          acc[p][0] = fmaf(a, w.x, acc[p][0]);
          acc[p][1] = fmaf(a, w.y, acc[p][1]);
        }
      }
    }
    float4 v = make_float4(acc[0][0], acc[0][1], acc[1][0], acc[1][1]);
    *(float4*)(s0 + g*256 + dp*4) = v;
    __syncthreads();
    if (t < 256) {
      int p = t >> 7, d = t & 127;
      float s = 0.f;
      #pragma unroll
      for (int kg = 0; kg < 8; ++kg) s += s0[kg*256 + (d>>1)*4 + p*2 + (d&1)];
      pf[((size_t)n*64 + tile*2 + p)*128 + d] = s + pb[d];
    }
  }
}

// ---------------- VQ argmin: dist' = |e|^2 - 2 f.e ----------------
__global__ __launch_bounds__(256) void k_vq(float* ws)
{
  __shared__ __align__(16) float fT[128*132];   // fT[d][rr]
  __shared__ __align__(16) float ech[64*128];   // ech[jj][d]
  __shared__ float ens[64];
  __shared__ float2 red[128*16];
  const float* pf  = ws + OFF_PF;
  const float* emT = ws + OFF_EMT;
  const float* en  = ws + OFF_EN;
  int* ind = (int*)(ws + OFF_IND);

  int t = threadIdx.x;
  int r0 = blockIdx.x * 128;
  for (int s = t; s < 16384; s += 256) {
    int rr = s >> 7, d = s & 127;
    fT[d*132 + rr] = pf[(size_t)(r0 + rr)*128 + d];
  }
  int rg = t & 15, jg = t >> 4;
  float bv[8]; int bi[8];
  #pragma unroll
  for (int r = 0; r < 8; ++r) { bv[r] = 3.4e38f; bi[r] = 0; }

  for (int ch = 0; ch < 16; ++ch) {
    __syncthreads();
    {
      const float4* src = (const float4*)(emT + (size_t)ch*8192);
      float4* dst = (float4*)ech;
      for (int q = t; q < 2048; q += 256) dst[q] = src[q];
      if (t < 64) ens[t] = en[ch*64 + t];
    }
    __syncthreads();
    float acc[8][4] = {};
    for (int db = 0; db < 128; db += 4) {
      float4 e0 = *(const float4*)(ech + (jg*4+0)*128 + db);
      float4 e1 = *(const float4*)(ech + (jg*4+1)*128 + db);
      float4 e2 = *(const float4*)(ech + (jg*4+2)*128 + db);
      float4 e3 = *(const float4*)(ech + (jg*4+3)*128 + db);
      #pragma unroll
      for (int u = 0; u < 4; ++u) {
        const float* fp = fT + (db+u)*132 + rg*8;
        float4 fa = *(const float4*)fp;
        float4 fb = *(const float4*)(fp + 4);
        float fv[8] = {fa.x,fa.y,fa.z,fa.w,fb.x,fb.y,fb.z,fb.w};
        float ev[4] = { ((const float*)&e0)[u], ((const float*)&e1)[u],
                        ((const float*)&e2)[u], ((const float*)&e3)[u] };
        #pragma unroll
        for (int r = 0; r < 8; ++r)
          #pragma unroll
          for (int j = 0; j < 4; ++j)
            acc[r][j] = fmaf(fv[r], ev[j], acc[r][j]);
      }
    }
    #pragma unroll
    for (int r = 0; r < 8; ++r)
      #pragma unroll
      for (int j = 0; j < 4; ++j) {
        float dist = ens[jg*4 + j] - 2.f*acc[r][j];
        int code = ch*64 + jg*4 + j;
        if (dist < bv[r]) { bv[r] = dist; bi[r] = code; }  // strict <: first index wins
      }
  }
  __syncthreads();
  #pragma unroll
  for (int r = 0; r < 8; ++r)
    red[(rg*8 + r)*16 + jg] = make_float2(bv[r], __int_as_float(bi[r]));
  __syncthreads();
  if (t < 128) {
    float2 v0 = red[t*16 + 0];
    float best = v0.x; int besti = __float_as_int(v0.y);
    for (int j = 1; j < 16; ++j) {
      float2 v = red[t*16 + j];
      int vi = __float_as_int(v.y);
      if (v.x < best || (v.x == best && vi < besti)) { best = v.x; besti = vi; }
    }
    ind[r0 + t] = besti;
  }
}

// ---------------- gather: z_q -> d_out, vq-loss partials ----------------
__global__ __launch_bounds__(256) void k_gather(float* ws, float* __restrict__ dout)
{
  const float* pf  = ws + OFF_PF;
  const float* emT = ws + OFF_EMT;
  const int* ind = (const int*)(ws + OFF_IND);
  float* vq_part = ws + OFF_VP;

  int t = threadIdx.x;
  int d = t & 127;
  float s = 0.f;
  #pragma unroll
  for (int it = 0; it < 4; ++it) {
    int rr = (t >> 7) + it*2;
    size_t row = (size_t)blockIdx.x*8 + rr;
    int idx = ind[row];
    float q = emT[(size_t)idx*128 + d];
    float f = pf[row*128 + d];
    float qm = q - f;
    dout[row*128 + d] = f + qm;
    s = fmaf(qm, qm, s);
  }
  __shared__ float sh[4];
  for (int o = 32; o; o >>= 1) s += __shfl_down(s, o, 64);
  if ((t & 63) == 0) sh[t >> 6] = s;
  __syncthreads();
  if (t == 0) vq_part[blockIdx.x] = sh[0]+sh[1]+sh[2]+sh[3];
}

// ---------------- decoder: tile=64, 512 threads, LDS ~59 KB ----------------
// block = (n, tile [0..15]); l in [l0, l0+64), patches p0-1 .. p0+4 (p0 = tile*4)
__global__ __launch_bounds__(512) void k_decoder(
    const float* __restrict__ zq, float* ws,
    const float* __restrict__ upb, const float* __restrict__ db1,
    const float* __restrict__ dw2, const float* __restrict__ db2)
{
  constexpr int UPS = 70;   // 68 cols used, l in [l0-2, l0+66)
  constexpr int DS  = 70;   // 66 cols used, l in [l0-1, l0+65)
  __shared__ __align__(16) float ztT[128*8];     // [e][pi], pi=0..5; later D2 scratch
  __shared__ __align__(16) float up_s[128*UPS];
  __shared__ __align__(16) float dsh[64*DS];     // first 3072 floats double as w1d chunk
  __shared__ __align__(16) float wd2[200];

  const float* upwT = ws + OFF_UPW;
  const float* w1dT = ws + OFF_W1D;
  const float* xn   = ws + OFF_XN;
  float* recon_part = ws + OFF_RP;

  int blk = blockIdx.x;
  int n = blk >> 4, tile = blk & 15;
  int l0 = tile*64, p0 = tile*4;
  int t = threadIdx.x;

  for (int s = t; s < 768; s += 512) {
    int e = s & 127, pi = s >> 7;
    int p = p0 - 1 + pi;
    ztT[e*8 + pi] = (p >= 0 && p < 64) ? zq[((size_t)n*64 + p)*128 + e] : 0.f;
  }
  if (t >= 768-512 && t < 768-512+512) {} // (single loop iteration covers 512; second covers 256)
  __syncthreads();

  // phase U: up[d][col] = sum_e z[p][e]*upw[e][d][j] + upb   (l = 16p+j)
  // thread: d = t&127, jq = t>>7 -> j in [4jq, 4jq+4)
  {
    int d = t & 127, jq = t >> 7;
    float acc[4][6] = {};
    const float* wbase = upwT + (size_t)jq*4*16384 + d;
    for (int e = 0; e < 128; ++e) {
      float4 z0 = *(const float4*)(ztT + e*8);
      float2 z1 = *(const float2*)(ztT + e*8 + 4);
      float zr[6] = {z0.x, z0.y, z0.z, z0.w, z1.x, z1.y};
      #pragma unroll
      for (int jj = 0; jj < 4; ++jj) {
        float w = wbase[(size_t)(jj*128 + e)*128];
        #pragma unroll
        for (int pi = 0; pi < 6; ++pi) acc[jj][pi] = fmaf(zr[pi], w, acc[jj][pi]);
      }
    }
    float ub = upb[d];
    #pragma unroll
    for (int jj = 0; jj < 4; ++jj)
      #pragma unroll
      for (int pi = 0; pi < 6; ++pi) {
        int j = jq*4 + jj;
        int l = (p0 - 1 + pi)*16 + j;
        int col = l - l0 + 2;
        if (col >= 0 && col < 68)
          up_s[d*UPS + col] = ((unsigned)l < 1024u) ? acc[jj][pi] + ub : 0.f;
      }
  }
  __syncthreads();

  // phase D1: d1[o][col] = gelu(conv3(up)+db1), col -> l = l0-1+col, 66 cols
  // thread: o-pair = t&31, q = t>>5 col-group (q0: 6 cols, else 4)
  int o2 = t & 31, q = t >> 5;
  int oA = 2*o2, oB = oA + 1;
  int colb = (q == 0) ? 0 : 4*q + 2;
  int ni   = (q == 0) ? 6 : 4;
  float accA[6] = {}, accB[6] = {};
  for (int cb = 0; cb < 8; ++cb) {
    __syncthreads();
    for (int s = t; s < 3072; s += 512) dsh[s] = w1dT[(size_t)cb*3072 + s];
    __syncthreads();
    for (int cl = 0; cl < 16; ++cl) {
      int c = cb*16 + cl;
      const float* row = up_s + c*UPS + colb;
      float r[8];
      #pragma unroll
      for (int x = 0; x < 8; x += 2) { float2 v = *(const float2*)(row + x); r[x]=v.x; r[x+1]=v.y; }
      float2 w0 = *(const float2*)(dsh + (cl*3+0)*64 + oA);
      float2 w1 = *(const float2*)(dsh + (cl*3+1)*64 + oA);
      float2 w2 = *(const float2*)(dsh + (cl*3+2)*64 + oA);
      #pragma unroll
      for (int i = 0; i < 6; ++i) {
        if (i < ni) {
          accA[i] = fmaf(w0.x, r[i], fmaf(w1.x, r[i+1], fmaf(w2.x, r[i+2], accA[i])));
          accB[i] = fmaf(w0.y, r[i], fmaf(w1.y, r[i+1], fmaf(w2.y, r[i+2], accB[i])));
        }
      }
    }
  }
  __syncthreads();   // all conv reads of dsh-as-weights & up_s done
  {
    float bA = db1[oA], bB = db1[oB];
    for (int i = 0; i < ni; ++i) {
      int col = colb + i;
      int l = l0 - 1 + col;
      float vA = 0.f, vB = 0.f;
      if ((unsigned)l < 1024u) {
        float xA = accA[i] + bA;
        vA = 0.5f*xA*(1.f + erff(xA*0.70710678118654752f));
        float xB = accB[i] + bB;
        vB = 0.5f*xB*(1.f + erff(xB*0.70710678118654752f));
      }
      dsh[oA*DS + col] = vA;
      dsh[oB*DS + col] = vB;
    }
  }
  if (t < 192) wd2[t] = dw2[t];
  __syncthreads();

  // phase D2 + recon partial: out l = l0 + loff
  if (t < 256) {
    int loff = t & 63, ch = t >> 6;
    float part = 0.f;
    for (int cl = 0; cl < 16; ++cl) {
      int c = ch*16 + cl;
      part = fmaf(wd2[c*3+0], dsh[c*DS + loff],
             fmaf(wd2[c*3+1], dsh[c*DS + loff + 1],
             fmaf(wd2[c*3+2], dsh[c*DS + loff + 2], part)));
    }
    ztT[loff*4 + ch] = part;   // ztT reused as scratch
  }
  __syncthreads();
  if (t < 64) {
    float acc = ztT[t*4+0] + ztT[t*4+1] + ztT[t*4+2] + ztT[t*4+3] + db2[0];
    float diff = acc - xn[(size_t)n*1024 + l0 + t];
    float part = diff*diff;
    for (int o = 32; o; o >>= 1) part += __shfl_down(part, o, 64);
    if (t == 0) recon_part[blk] = part;
  }
}

// ---------------- finalize loss ----------------
__global__ __launch_bounds__(256) void k_finalize(const float* __restrict__ ws, float* __restrict__ dout)
{
  const float* rp = ws + OFF_RP;
  const float* vp = ws + OFF_VP;
  int t = threadIdx.x;
  float s1 = 0.f, s2 = 0.f;
  for (int i = t; i < 8192; i += 256) s1 += rp[i];
  for (int i = t; i < 4096; i += 256) s2 += vp[i];
  __shared__ float sh[8];
  for (int o = 32; o; o >>= 1) { s1 += __shfl_down(s1,o,64); s2 += __shfl_down(s2,o,64); }
  if ((t & 63) == 0) { sh[t >> 6] = s1; sh[4 + (t >> 6)] = s2; }
  __syncthreads();
  if (t == 0) {
    float R = sh[0]+sh[1]+sh[2]+sh[3];
    float V = sh[4]+sh[5]+sh[6]+sh[7];
    dout[4194304] = R * (1.f/524288.f) + 0.25f * (V * (1.f/4194304.f));
  }
}

// ---------------- host ----------------
extern "C" void kernel_launch(void* const* d_in, const int* in_sizes, int n_in,
                              void* d_out, int out_size, void* d_ws, size_t ws_size,
                              hipStream_t stream)
{
  const float* x    = (const float*)d_in[0];
  const float* rw   = (const float*)d_in[1];
  const float* rb   = (const float*)d_in[2];
  const float* w1a  = (const float*)d_in[3];
  const float* b1a  = (const float*)d_in[4];
  const float* w2a  = (const float*)d_in[5];
  const float* b2a  = (const float*)d_in[6];
  const float* wda  = (const float*)d_in[7];
  const float* bda  = (const float*)d_in[8];
  const float* w1b  = (const float*)d_in[9];
  const float* b1b  = (const float*)d_in[10];
  const float* w2b  = (const float*)d_in[11];
  const float* b2b  = (const float*)d_in[12];
  const float* pw   = (const float*)d_in[13];
  const float* pb   = (const float*)d_in[14];
  const float* em   = (const float*)d_in[15];
  const float* upw  = (const float*)d_in[16];
  const float* upb  = (const float*)d_in[17];
  const float* dw1  = (const float*)d_in[18];
  const float* db1  = (const float*)d_in[19];
  const float* dw2  = (const float*)d_in[20];
  const float* db2  = (const float*)d_in[21];
  float* ws = (float*)d_ws;
  float* out = (float*)d_out;

  k_prep<<<256, 256, 0, stream>>>(w2a, w1b, w2b, pw, upw, dw1, em, ws);
  k_revin<<<512, 256, 0, stream>>>(x, rw, rb, ws + OFF_XN);
  k_encoder<<<16384, 512, 0, stream>>>(ws, w1a, b1a, b2a, wda, bda, b1b, b2b, pb);
  k_vq<<<256, 256, 0, stream>>>(ws);
  k_gather<<<4096, 256, 0, stream>>>(ws, out);
  k_decoder<<<8192, 512, 0, stream>>>(out, ws, upb, db1, dw2, db2);
  k_finalize<<<1, 256, 0, stream>>>(ws, out);
}

// Round 4
// 5135.860 us; speedup vs baseline: 1.1884x; 1.1884x over previous
//
#include <hip/hip_runtime.h>

// ---------------- workspace layout (floats) ----------------
constexpr size_t OFF_XN  = 0;                      // 512*1024
constexpr size_t OFF_PF  = 524288;                 // 32768*128
constexpr size_t OFF_W2A = OFF_PF  + 4194304;      // [(cc*3+k)*128+d]
constexpr size_t OFF_W1B = OFF_W2A + 49152;
constexpr size_t OFF_W2B = OFF_W1B + 49152;
constexpr size_t OFF_PW  = OFF_W2B + 49152;        // [(c*16+k)*128+d]
constexpr size_t OFF_UPW = OFF_PW  + 262144;       // [(j*128+e)*128+d]
constexpr size_t OFF_W1D = OFF_UPW + 262144;       // [(c*3+k)*64+o]
constexpr size_t OFF_EMT = OFF_W1D + 24576;        // [j*128+d]
constexpr size_t OFF_EN  = OFF_EMT + 131072;       // 1024
constexpr size_t OFF_RP  = OFF_EN  + 1024;         // 8192
constexpr size_t OFF_VP  = OFF_RP  + 8192;         // 4096
constexpr size_t OFF_IND = OFF_VP  + 4096;         // 32768 int
constexpr size_t OFF_A   = OFF_IND + 32768;        // 64*128*1024 (h1a/h1b; aliases pfpart)
constexpr size_t OFF_B   = OFF_A + 8388608;        // 64*128*1024 (out0 -> out1)
// total = 22,369,280 floats = 89.5 MB (same as round-0 proven footprint)

#define DI __device__ __forceinline__

// ---------------- prep: weight transposes + embedT + |e|^2 ----------------
__global__ __launch_bounds__(256) void k_prep(
    const float* __restrict__ w2a, const float* __restrict__ w1b, const float* __restrict__ w2b,
    const float* __restrict__ pw,  const float* __restrict__ upw, const float* __restrict__ w1d,
    const float* __restrict__ em,  float* __restrict__ ws)
{
  int tid = blockIdx.x * 256 + threadIdx.x;
  int stride = gridDim.x * 256;
  for (int i = tid; i < 128*128*3; i += stride) {
    int d = i / 384, r = i % 384;          // r = cc*3+k
    ws[OFF_W2A + (size_t)r*128 + d] = w2a[i];
    ws[OFF_W1B + (size_t)r*128 + d] = w1b[i];
    ws[OFF_W2B + (size_t)r*128 + d] = w2b[i];
  }
  for (int i = tid; i < 128*128*16; i += stride) {
    int d = i / 2048, r = i % 2048;        // r = c*16+k
    ws[OFF_PW + (size_t)r*128 + d] = pw[i];
  }
  for (int i = tid; i < 128*128*16; i += stride) {
    int e = i / 2048, rem = i % 2048;
    int d = rem / 16, j = rem % 16;
    ws[OFF_UPW + (size_t)(j*128 + e)*128 + d] = upw[i];
  }
  for (int i = tid; i < 64*128*3; i += stride) {
    int o = i / 384, r = i % 384;          // r = c*3+k
    ws[OFF_W1D + (size_t)r*64 + o] = w1d[i];
  }
  for (int j = tid; j < 1024; j += stride) {
    float s = 0.f;
    for (int d = 0; d < 128; ++d) {
      float v = em[d*1024 + j];
      ws[OFF_EMT + (size_t)j*128 + d] = v;
      s = fmaf(v, v, s);
    }
    ws[OFF_EN + j] = s;
  }
}

// ---------------- RevIN ----------------
__global__ __launch_bounds__(256) void k_revin(
    const float* __restrict__ x, const float* __restrict__ rw, const float* __restrict__ rb,
    float* __restrict__ xn)
{
  int n = blockIdx.x;            // sample = b*8 + c
  int b = n >> 3, c = n & 7;
  int t = threadIdx.x;
  const float* xp = x + (size_t)b*8192 + c;
  float v[4]; float s = 0.f, s2 = 0.f;
  #pragma unroll
  for (int i = 0; i < 4; ++i) {
    v[i] = xp[(size_t)(t + i*256)*8];
    s += v[i]; s2 = fmaf(v[i], v[i], s2);
  }
  __shared__ float sh[8];
  __shared__ float st[2];
  for (int o = 32; o; o >>= 1) { s += __shfl_down(s, o, 64); s2 += __shfl_down(s2, o, 64); }
  if ((t & 63) == 0) { sh[t >> 6] = s; sh[4 + (t >> 6)] = s2; }
  __syncthreads();
  if (t == 0) {
    float S = sh[0]+sh[1]+sh[2]+sh[3];
    float S2 = sh[4]+sh[5]+sh[6]+sh[7];
    float mu = S * (1.f/1024.f);
    float var = S2 * (1.f/1024.f) - mu*mu;
    st[0] = mu;
    st[1] = 1.f / sqrtf(var + 1e-5f);
  }
  __syncthreads();
  float mu = st[0], inv = st[1], w0 = rw[0], b0 = rb[0];
  #pragma unroll
  for (int i = 0; i < 4; ++i)
    xn[(size_t)n*1024 + t + i*256] = fmaf((v[i]-mu)*inv, w0, b0);
}

// ---------------- K1: h1a = relu(conv3(xn) + b1a), 1 input channel ----------------
// grid: 64 nloc x 4 Lq; block 512: thread = (c = t&127, seg = t>>7) -> 64 cols
__global__ __launch_bounds__(512) void k_h1a(
    const float* __restrict__ xn, float* __restrict__ A,
    const float* __restrict__ w1a, const float* __restrict__ b1a, int n0)
{
  __shared__ float xs[260];
  int nloc = blockIdx.x >> 2, Lq = blockIdx.x & 3;
  int n = n0 + nloc;
  int L0 = Lq * 256;
  int t = threadIdx.x;
  if (t < 258) {
    int gl = L0 - 2 + t;
    xs[t] = (gl >= 0) ? xn[(size_t)n*1024 + gl] : 0.f;
  }
  __syncthreads();
  int c = t & 127, seg = t >> 7;
  float w0 = w1a[c*3+0], w1 = w1a[c*3+1], w2 = w1a[c*3+2], b = b1a[c];
  float* dst = A + (size_t)nloc*131072 + (size_t)c*1024 + L0 + seg*64;
  const float* sx = xs + seg*64;
  float xm2 = sx[0], xm1 = sx[1];
  for (int i = 0; i < 64; i += 4) {
    float4 o;
    float x0;
    x0 = sx[i+2]; o.x = fmaxf(fmaf(w0,xm2,fmaf(w1,xm1,fmaf(w2,x0,b))),0.f); xm2=xm1; xm1=x0;
    x0 = sx[i+3]; o.y = fmaxf(fmaf(w0,xm2,fmaf(w1,xm1,fmaf(w2,x0,b))),0.f); xm2=xm1; xm1=x0;
    x0 = sx[i+4]; o.z = fmaxf(fmaf(w0,xm2,fmaf(w1,xm1,fmaf(w2,x0,b))),0.f); xm2=xm1; xm1=x0;
    x0 = sx[i+5]; o.w = fmaxf(fmaf(w0,xm2,fmaf(w1,xm1,fmaf(w2,x0,b))),0.f); xm2=xm1; xm1=x0;
    *(float4*)(dst + i) = o;
  }
}

// ---------------- K2/K3/K4: 128ch causal conv3, lane=col, waves=(cc-half x d-quarter) ----
// MODE 2: out0 = relu(relu(acc+bias) + wd*xn+bd)
// MODE 3: h1b  = relu(acc+bias)
// MODE 4: out1 = relu(relu(acc+bias) + out[same addr]) (residual=out0, written in place)
template<int MODE>
__global__ __launch_bounds__(512) void k_conv(
    const float* __restrict__ in, float* __restrict__ out,
    const float* __restrict__ wT, const float* __restrict__ bias,
    const float* __restrict__ wd, const float* __restrict__ bd,
    const float* __restrict__ xn, int n0)
{
  __shared__ float lds[128*66];   // input tile; reused as exch[4][32][64] (32KB <= 33.8KB)
  int nloc = blockIdx.x >> 4, tile = blockIdx.x & 15;
  int n = n0 + nloc;
  int l0 = tile * 64;
  int t = threadIdx.x;
  const float* inb = in + (size_t)nloc*131072;
  // stage [128cc][66 cols]: global cols l0-2 .. l0+64 (left causal pad -> 0)
  {
    int row = t & 127, seg = t >> 7;
    const float* src = inb + (size_t)row*1024 + l0 - 2;
    for (int j = seg*17; j < seg*17+17; ++j) {
      if (j < 66) {
        int gl = l0 - 2 + j;
        lds[row*66 + j] = (gl >= 0) ? src[j] : 0.f;
      }
    }
  }
  __syncthreads();
  int lane = t & 63;
  int w = __builtin_amdgcn_readfirstlane(t >> 6);
  int cch = w & 1, dq = w >> 1;
  int ccb = cch * 64, d0 = dq * 32;
  float acc[32];
  #pragma unroll
  for (int i = 0; i < 32; ++i) acc[i] = 0.f;

  for (int cc = ccb; cc < ccb + 64; ++cc) {
    float r0 = lds[cc*66 + lane];
    float r1 = lds[cc*66 + lane + 1];
    float r2 = lds[cc*66 + lane + 2];
    const float* wp = wT + (size_t)cc*384 + d0;
    #pragma unroll
    for (int j = 0; j < 8; ++j) {
      float4 w0 = *(const float4*)(wp + j*4);
      float4 w1 = *(const float4*)(wp + 128 + j*4);
      float4 w2 = *(const float4*)(wp + 256 + j*4);
      acc[j*4+0] = fmaf(w0.x, r0, fmaf(w1.x, r1, fmaf(w2.x, r2, acc[j*4+0])));
      acc[j*4+1] = fmaf(w0.y, r0, fmaf(w1.y, r1, fmaf(w2.y, r2, acc[j*4+1])));
      acc[j*4+2] = fmaf(w0.z, r0, fmaf(w1.z, r1, fmaf(w2.z, r2, acc[j*4+2])));
      acc[j*4+3] = fmaf(w0.w, r0, fmaf(w1.w, r1, fmaf(w2.w, r2, acc[j*4+3])));
    }
  }
  __syncthreads();      // all data reads done; lds becomes exchange buffer
  if (cch) {
    #pragma unroll
    for (int i = 0; i < 32; ++i) lds[dq*2048 + i*64 + lane] = acc[i];
  }
  __syncthreads();
  if (!cch) {
    float* ob = out + (size_t)nloc*131072 + (size_t)d0*1024 + l0 + lane;
    float xv = 0.f;
    if (MODE == 2) xv = xn[(size_t)n*1024 + l0 + lane];
    #pragma unroll 4
    for (int i = 0; i < 32; ++i) {
      int d = d0 + i;
      float s = acc[i] + lds[dq*2048 + i*64 + lane] + bias[d];
      float o;
      if (MODE == 2) {
        o = fmaxf(fmaxf(s, 0.f) + fmaf(wd[d], xv, bd[d]), 0.f);
      } else if (MODE == 3) {
        o = fmaxf(s, 0.f);
      } else {
        float res = ob[(size_t)i*1024];   // out0 at same address (owned by this thread)
        o = fmaxf(fmaxf(s, 0.f) + res, 0.f);
      }
      ob[(size_t)i*1024] = o;
    }
  }
}

// ---------------- K5: patchify GEMM partial. block=(nloc 64 x cq 4), 256 thr ----------
// pfpart[cq][nloc*64+p][d] = sum over c in [cq*32, cq*32+32), k16 of out1[n][c][16p+k]*pwT
__global__ __launch_bounds__(256) void k_pfy(
    const float* __restrict__ B, const float* __restrict__ pwT, float* __restrict__ pfp)
{
  __shared__ float as[64*64];   // [Kloc 64][p 64]
  int nloc = blockIdx.x >> 2, cq = blockIdx.x & 3;
  int t = threadIdx.x;
  int rq = t >> 4, dg = t & 15;
  float acc[4][8];
  #pragma unroll
  for (int r = 0; r < 4; ++r)
    #pragma unroll
    for (int m = 0; m < 8; ++m) acc[r][m] = 0.f;

  const float* src = B + (size_t)nloc*131072 + (size_t)cq*32*1024;
  for (int cci = 0; cci < 8; ++cci) {
    __syncthreads();
    {
      int cloc = t >> 6, p = t & 63;
      const float4* s4 = (const float4*)(src + (size_t)(cci*4 + cloc)*1024 + p*16);
      float4 v0 = s4[0], v1 = s4[1], v2 = s4[2], v3 = s4[3];
      float vv[16] = {v0.x,v0.y,v0.z,v0.w, v1.x,v1.y,v1.z,v1.w,
                      v2.x,v2.y,v2.z,v2.w, v3.x,v3.y,v3.z,v3.w};
      #pragma unroll
      for (int k = 0; k < 16; ++k) as[(cloc*16 + k)*64 + p] = vv[k];
    }
    __syncthreads();
    const float* wbase = pwT + ((size_t)(cq*32 + cci*4)*16)*128 + dg*8;
    for (int K = 0; K < 64; ++K) {
      float4 a4 = *(const float4*)(as + K*64 + rq*4);
      float4 wA = *(const float4*)(wbase + (size_t)K*128);
      float4 wB = *(const float4*)(wbase + (size_t)K*128 + 4);
      float av[4] = {a4.x, a4.y, a4.z, a4.w};
      #pragma unroll
      for (int r = 0; r < 4; ++r) {
        acc[r][0] = fmaf(av[r], wA.x, acc[r][0]);
        acc[r][1] = fmaf(av[r], wA.y, acc[r][1]);
        acc[r][2] = fmaf(av[r], wA.z, acc[r][2]);
        acc[r][3] = fmaf(av[r], wA.w, acc[r][3]);
        acc[r][4] = fmaf(av[r], wB.x, acc[r][4]);
        acc[r][5] = fmaf(av[r], wB.y, acc[r][5]);
        acc[r][6] = fmaf(av[r], wB.z, acc[r][6]);
        acc[r][7] = fmaf(av[r], wB.w, acc[r][7]);
      }
    }
  }
  #pragma unroll
  for (int r = 0; r < 4; ++r) {
    float* dst = pfp + ((size_t)cq*4096 + nloc*64 + rq*4 + r)*128 + dg*8;
    float4 o1 = make_float4(acc[r][0], acc[r][1], acc[r][2], acc[r][3]);
    float4 o2 = make_float4(acc[r][4], acc[r][5], acc[r][6], acc[r][7]);
    *(float4*)dst = o1;
    *(float4*)(dst + 4) = o2;
  }
}

// ---------------- K5r: reduce 4 K-splits + bias -> pf ----------------
__global__ __launch_bounds__(256) void k_pfred(
    const float* __restrict__ pfp, const float* __restrict__ pb,
    float* __restrict__ pf, int row0)
{
  int idx = blockIdx.x * 256 + threadIdx.x;   // x8 floats
  size_t base = (size_t)idx * 8;
  int d = (int)(base & 127);
  float4 s0 = *(const float4*)(pfp + base);
  float4 s1 = *(const float4*)(pfp + base + 4);
  #pragma unroll
  for (int cq = 1; cq < 4; ++cq) {
    float4 a0 = *(const float4*)(pfp + (size_t)cq*524288 + base);
    float4 a1 = *(const float4*)(pfp + (size_t)cq*524288 + base + 4);
    s0.x += a0.x; s0.y += a0.y; s0.z += a0.z; s0.w += a0.w;
    s1.x += a1.x; s1.y += a1.y; s1.z += a1.z; s1.w += a1.w;
  }
  float4 b0 = *(const float4*)(pb + d);
  float4 b1 = *(const float4*)(pb + d + 4);
  s0.x += b0.x; s0.y += b0.y; s0.z += b0.z; s0.w += b0.w;
  s1.x += b1.x; s1.y += b1.y; s1.z += b1.z; s1.w += b1.w;
  float* dst = pf + (size_t)row0*128 + base;
  *(float4*)dst = s0;
  *(float4*)(dst + 4) = s1;
}

// ---------------- VQ argmin: dist' = |e|^2 - 2 f.e ----------------
__global__ __launch_bounds__(256) void k_vq(float* ws)
{
  __shared__ __align__(16) float fT[128*132];   // fT[d][rr]
  __shared__ __align__(16) float ech[64*128];   // [jj][d], XOR-swizzled by row
  __shared__ float ens[64];
  __shared__ float2 red[128*16];
  const float* pf  = ws + OFF_PF;
  const float* emT = ws + OFF_EMT;
  const float* en  = ws + OFF_EN;
  int* ind = (int*)(ws + OFF_IND);

  int t = threadIdx.x;
  int r0 = blockIdx.x * 128;
  for (int s = t; s < 16384; s += 256) {
    int rr = s >> 7, d = s & 127;
    fT[d*132 + rr] = pf[(size_t)(r0 + rr)*128 + d];
  }
  int rg = t & 15, jg = t >> 4;
  float bv[8]; int bi[8];
  #pragma unroll
  for (int r = 0; r < 8; ++r) { bv[r] = 3.4e38f; bi[r] = 0; }

  for (int ch = 0; ch < 16; ++ch) {
    __syncthreads();
    {
      const float4* src = (const float4*)(emT + (size_t)ch*8192);
      for (int q = t; q < 2048; q += 256) {
        int jj = q >> 5, dq4 = q & 31;
        *(float4*)(ech + jj*128 + ((dq4*4) ^ ((jj&7)<<2))) = src[q];
      }
      if (t < 64) ens[t] = en[ch*64 + t];
    }
    __syncthreads();
    float acc[8][4] = {};
    for (int db = 0; db < 128; db += 4) {
      float4 e0 = *(const float4*)(ech + (jg*4+0)*128 + (db ^ (((jg*4+0)&7)<<2)));
      float4 e1 = *(const float4*)(ech + (jg*4+1)*128 + (db ^ (((jg*4+1)&7)<<2)));
      float4 e2 = *(const float4*)(ech + (jg*4+2)*128 + (db ^ (((jg*4+2)&7)<<2)));
      float4 e3 = *(const float4*)(ech + (jg*4+3)*128 + (db ^ (((jg*4+3)&7)<<2)));
      #pragma unroll
      for (int u = 0; u < 4; ++u) {
        const float* fp = fT + (db+u)*132 + rg*8;
        float4 fa = *(const float4*)fp;
        float4 fb = *(const float4*)(fp + 4);
        float fv[8] = {fa.x,fa.y,fa.z,fa.w,fb.x,fb.y,fb.z,fb.w};
        float ev[4] = { ((const float*)&e0)[u], ((const float*)&e1)[u],
                        ((const float*)&e2)[u], ((const float*)&e3)[u] };
        #pragma unroll
        for (int r = 0; r < 8; ++r)
          #pragma unroll
          for (int j = 0; j < 4; ++j)
            acc[r][j] = fmaf(fv[r], ev[j], acc[r][j]);
      }
    }
    #pragma unroll
    for (int r = 0; r < 8; ++r)
      #pragma unroll
      for (int j = 0; j < 4; ++j) {
        float dist = ens[jg*4 + j] - 2.f*acc[r][j];
        int code = ch*64 + jg*4 + j;
        if (dist < bv[r]) { bv[r] = dist; bi[r] = code; }  // strict <: first index wins
      }
  }
  __syncthreads();
  #pragma unroll
  for (int r = 0; r < 8; ++r)
    red[(rg*8 + r)*16 + jg] = make_float2(bv[r], __int_as_float(bi[r]));
  __syncthreads();
  if (t < 128) {
    float2 v0 = red[t*16 + 0];
    float best = v0.x; int besti = __float_as_int(v0.y);
    for (int j = 1; j < 16; ++j) {
      float2 v = red[t*16 + j];
      int vi = __float_as_int(v.y);
      if (v.x < best || (v.x == best && vi < besti)) { best = v.x; besti = vi; }
    }
    ind[r0 + t] = besti;
  }
}

// ---------------- gather: z_q -> d_out, vq-loss partials ----------------
__global__ __launch_bounds__(256) void k_gather(float* ws, float* __restrict__ dout)
{
  const float* pf  = ws + OFF_PF;
  const float* emT = ws + OFF_EMT;
  const int* ind = (const int*)(ws + OFF_IND);
  float* vq_part = ws + OFF_VP;

  int t = threadIdx.x;
  int d = t & 127;
  float s = 0.f;
  #pragma unroll
  for (int it = 0; it < 4; ++it) {
    int rr = (t >> 7) + it*2;
    size_t row = (size_t)blockIdx.x*8 + rr;
    int idx = ind[row];
    float q = emT[(size_t)idx*128 + d];
    float f = pf[row*128 + d];
    float qm = q - f;
    dout[row*128 + d] = f + qm;
    s = fmaf(qm, qm, s);
  }
  __shared__ float sh[4];
  for (int o = 32; o; o >>= 1) s += __shfl_down(s, o, 64);
  if ((t & 63) == 0) sh[t >> 6] = s;
  __syncthreads();
  if (t == 0) vq_part[blockIdx.x] = sh[0]+sh[1]+sh[2]+sh[3];
}

// ---------------- decoder: tile=64, 512 threads (unchanged from R3) ----------------
__global__ __launch_bounds__(512) void k_decoder(
    const float* __restrict__ zq, float* ws,
    const float* __restrict__ upb, const float* __restrict__ db1,
    const float* __restrict__ dw2, const float* __restrict__ db2)
{
  constexpr int UPS = 70;
  constexpr int DS  = 70;
  __shared__ __align__(16) float ztT[128*8];
  __shared__ __align__(16) float up_s[128*UPS];
  __shared__ __align__(16) float dsh[64*DS];
  __shared__ __align__(16) float wd2[200];

  const float* upwT = ws + OFF_UPW;
  const float* w1dT = ws + OFF_W1D;
  const float* xn   = ws + OFF_XN;
  float* recon_part = ws + OFF_RP;

  int blk = blockIdx.x;
  int n = blk >> 4, tile = blk & 15;
  int l0 = tile*64, p0 = tile*4;
  int t = threadIdx.x;

  for (int s = t; s < 768; s += 512) {
    int e = s & 127, pi = s >> 7;
    int p = p0 - 1 + pi;
    ztT[e*8 + pi] = (p >= 0 && p < 64) ? zq[((size_t)n*64 + p)*128 + e] : 0.f;
  }
  __syncthreads();

  {
    int d = t & 127, jq = t >> 7;
    float acc[4][6] = {};
    const float* wbase = upwT + (size_t)jq*4*16384 + d;
    for (int e = 0; e < 128; ++e) {
      float4 z0 = *(const float4*)(ztT + e*8);
      float2 z1 = *(const float2*)(ztT + e*8 + 4);
      float zr[6] = {z0.x, z0.y, z0.z, z0.w, z1.x, z1.y};
      #pragma unroll
      for (int jj = 0; jj < 4; ++jj) {
        float w = wbase[(size_t)(jj*128 + e)*128];
        #pragma unroll
        for (int pi = 0; pi < 6; ++pi) acc[jj][pi] = fmaf(zr[pi], w, acc[jj][pi]);
      }
    }
    float ub = upb[d];
    #pragma unroll
    for (int jj = 0; jj < 4; ++jj)
      #pragma unroll
      for (int pi = 0; pi < 6; ++pi) {
        int j = jq*4 + jj;
        int l = (p0 - 1 + pi)*16 + j;
        int col = l - l0 + 2;
        if (col >= 0 && col < 68)
          up_s[d*UPS + col] = ((unsigned)l < 1024u) ? acc[jj][pi] + ub : 0.f;
      }
  }
  __syncthreads();

  int o2 = t & 31, q = t >> 5;
  int oA = 2*o2, oB = oA + 1;
  int colb = (q == 0) ? 0 : 4*q + 2;
  int ni   = (q == 0) ? 6 : 4;
  float accA[6] = {}, accB[6] = {};
  for (int cb = 0; cb < 8; ++cb) {
    __syncthreads();
    for (int s = t; s < 3072; s += 512) dsh[s] = w1dT[(size_t)cb*3072 + s];
    __syncthreads();
    for (int cl = 0; cl < 16; ++cl) {
      int c = cb*16 + cl;
      const float* row = up_s + c*UPS + colb;
      float r[8];
      #pragma unroll
      for (int x = 0; x < 8; x += 2) { float2 v = *(const float2*)(row + x); r[x]=v.x; r[x+1]=v.y; }
      float2 w0 = *(const float2*)(dsh + (cl*3+0)*64 + oA);
      float2 w1 = *(const float2*)(dsh + (cl*3+1)*64 + oA);
      float2 w2 = *(const float2*)(dsh + (cl*3+2)*64 + oA);
      #pragma unroll
      for (int i = 0; i < 6; ++i) {
        if (i < ni) {
          accA[i] = fmaf(w0.x, r[i], fmaf(w1.x, r[i+1], fmaf(w2.x, r[i+2], accA[i])));
          accB[i] = fmaf(w0.y, r[i], fmaf(w1.y, r[i+1], fmaf(w2.y, r[i+2], accB[i])));
        }
      }
    }
  }
  __syncthreads();
  {
    float bA = db1[oA], bB = db1[oB];
    for (int i = 0; i < ni; ++i) {
      int col = colb + i;
      int l = l0 - 1 + col;
      float vA = 0.f, vB = 0.f;
      if ((unsigned)l < 1024u) {
        float xA = accA[i] + bA;
        vA = 0.5f*xA*(1.f + erff(xA*0.70710678118654752f));
        float xB = accB[i] + bB;
        vB = 0.5f*xB*(1.f + erff(xB*0.70710678118654752f));
      }
      dsh[oA*DS + col] = vA;
      dsh[oB*DS + col] = vB;
    }
  }
  if (t < 192) wd2[t] = dw2[t];
  __syncthreads();

  if (t < 256) {
    int loff = t & 63, ch = t >> 6;
    float part = 0.f;
    for (int cl = 0; cl < 16; ++cl) {
      int c = ch*16 + cl;
      part = fmaf(wd2[c*3+0], dsh[c*DS + loff],
             fmaf(wd2[c*3+1], dsh[c*DS + loff + 1],
             fmaf(wd2[c*3+2], dsh[c*DS + loff + 2], part)));
    }
    ztT[loff*4 + ch] = part;
  }
  __syncthreads();
  if (t < 64) {
    float acc = ztT[t*4+0] + ztT[t*4+1] + ztT[t*4+2] + ztT[t*4+3] + db2[0];
    float diff = acc - xn[(size_t)n*1024 + l0 + t];
    float part = diff*diff;
    for (int o = 32; o; o >>= 1) part += __shfl_down(part, o, 64);
    if (t == 0) recon_part[blk] = part;
  }
}

// ---------------- finalize loss ----------------
__global__ __launch_bounds__(256) void k_finalize(const float* __restrict__ ws, float* __restrict__ dout)
{
  const float* rp = ws + OFF_RP;
  const float* vp = ws + OFF_VP;
  int t = threadIdx.x;
  float s1 = 0.f, s2 = 0.f;
  for (int i = t; i < 8192; i += 256) s1 += rp[i];
  for (int i = t; i < 4096; i += 256) s2 += vp[i];
  __shared__ float sh[8];
  for (int o = 32; o; o >>= 1) { s1 += __shfl_down(s1,o,64); s2 += __shfl_down(s2,o,64); }
  if ((t & 63) == 0) { sh[t >> 6] = s1; sh[4 + (t >> 6)] = s2; }
  __syncthreads();
  if (t == 0) {
    float R = sh[0]+sh[1]+sh[2]+sh[3];
    float V = sh[4]+sh[5]+sh[6]+sh[7];
    dout[4194304] = R * (1.f/524288.f) + 0.25f * (V * (1.f/4194304.f));
  }
}

// ---------------- host ----------------
extern "C" void kernel_launch(void* const* d_in, const int* in_sizes, int n_in,
                              void* d_out, int out_size, void* d_ws, size_t ws_size,
                              hipStream_t stream)
{
  const float* x    = (const float*)d_in[0];
  const float* rw   = (const float*)d_in[1];
  const float* rb   = (const float*)d_in[2];
  const float* w1a  = (const float*)d_in[3];
  const float* b1a  = (const float*)d_in[4];
  const float* w2a  = (const float*)d_in[5];
  const float* b2a  = (const float*)d_in[6];
  const float* wda  = (const float*)d_in[7];
  const float* bda  = (const float*)d_in[8];
  const float* w1b  = (const float*)d_in[9];
  const float* b1b  = (const float*)d_in[10];
  const float* w2b  = (const float*)d_in[11];
  const float* b2b  = (const float*)d_in[12];
  const float* pw   = (const float*)d_in[13];
  const float* pb   = (const float*)d_in[14];
  const float* em   = (const float*)d_in[15];
  const float* upw  = (const float*)d_in[16];
  const float* upb  = (const float*)d_in[17];
  const float* dw1  = (const float*)d_in[18];
  const float* db1  = (const float*)d_in[19];
  const float* dw2  = (const float*)d_in[20];
  const float* db2  = (const float*)d_in[21];
  float* ws = (float*)d_ws;
  float* out = (float*)d_out;

  float* xn   = ws + OFF_XN;
  float* A    = ws + OFF_A;
  float* B    = ws + OFF_B;
  float* pfp  = ws + OFF_A;          // pfpart aliases A (h1b dead by K5)
  float* pf   = ws + OFF_PF;
  const float* w2aT = ws + OFF_W2A;
  const float* w1bT = ws + OFF_W1B;
  const float* w2bT = ws + OFF_W2B;
  const float* pwT  = ws + OFF_PW;

  k_prep<<<256, 256, 0, stream>>>(w2a, w1b, w2b, pw, upw, dw1, em, ws);
  k_revin<<<512, 256, 0, stream>>>(x, rw, rb, xn);
  for (int nc = 0; nc < 8; ++nc) {
    int n0 = nc * 64;
    k_h1a<<<256, 512, 0, stream>>>(xn, A, w1a, b1a, n0);
    k_conv<2><<<1024, 512, 0, stream>>>(A, B, w2aT, b2a, wda, bda, xn, n0);
    k_conv<3><<<1024, 512, 0, stream>>>(B, A, w1bT, b1b, nullptr, nullptr, nullptr, n0);
    k_conv<4><<<1024, 512, 0, stream>>>(A, B, w2bT, b2b, nullptr, nullptr, nullptr, n0);
    k_pfy<<<256, 256, 0, stream>>>(B, pwT, pfp);
    k_pfred<<<256, 256, 0, stream>>>(pfp, pb, pf, nc*4096);
  }
  k_vq<<<256, 256, 0, stream>>>(ws);
  k_gather<<<4096, 256, 0, stream>>>(ws, out);
  k_decoder<<<8192, 512, 0, stream>>>(out, ws, upb, db1, dw2, db2);
  k_finalize<<<1, 256, 0, stream>>>(ws, out);
}

// Round 5
// 4434.810 us; speedup vs baseline: 1.3763x; 1.1581x over previous
//
#include <hip/hip_runtime.h>

// ---------------- workspace layout (floats) ----------------
constexpr size_t OFF_XN  = 0;                      // 512*1024
constexpr size_t OFF_PF  = 524288;                 // 32768*128
constexpr size_t OFF_W2A = OFF_PF  + 4194304;      // [(cc*3+k)*128+d]
constexpr size_t OFF_W1B = OFF_W2A + 49152;
constexpr size_t OFF_W2B = OFF_W1B + 49152;
constexpr size_t OFF_PW  = OFF_W2B + 49152;        // [(c*16+k)*128+d]
constexpr size_t OFF_UPW = OFF_PW  + 262144;       // [(j*128+e)*128+d]
constexpr size_t OFF_W1D = OFF_UPW + 262144;       // [(c*3+k)*64+o]
constexpr size_t OFF_EMT = OFF_W1D + 24576;        // [j*128+d]
constexpr size_t OFF_EN  = OFF_EMT + 131072;       // 1024
constexpr size_t OFF_RP  = OFF_EN  + 1024;         // 8192
constexpr size_t OFF_VP  = OFF_RP  + 8192;         // 4096
constexpr size_t OFF_IND = OFF_VP  + 4096;         // 32768 int
constexpr size_t OFF_A   = OFF_IND + 32768;        // 64*128*1024 out1
constexpr size_t OFF_B   = OFF_A + 8388608;        // 64*128*1024 out0 (later pfp)
// total = 22,369,280 floats = 89.5 MB

#define DI __device__ __forceinline__

// ---------------- prep: weight transposes + embedT + |e|^2 ----------------
__global__ __launch_bounds__(256) void k_prep(
    const float* __restrict__ w2a, const float* __restrict__ w1b, const float* __restrict__ w2b,
    const float* __restrict__ pw,  const float* __restrict__ upw, const float* __restrict__ w1d,
    const float* __restrict__ em,  float* __restrict__ ws)
{
  int tid = blockIdx.x * 256 + threadIdx.x;
  int stride = gridDim.x * 256;
  for (int i = tid; i < 128*128*3; i += stride) {
    int d = i / 384, r = i % 384;          // r = cc*3+k
    ws[OFF_W2A + (size_t)r*128 + d] = w2a[i];
    ws[OFF_W1B + (size_t)r*128 + d] = w1b[i];
    ws[OFF_W2B + (size_t)r*128 + d] = w2b[i];
  }
  for (int i = tid; i < 128*128*16; i += stride) {
    int d = i / 2048, r = i % 2048;        // r = c*16+k
    ws[OFF_PW + (size_t)r*128 + d] = pw[i];
  }
  for (int i = tid; i < 128*128*16; i += stride) {
    int e = i / 2048, rem = i % 2048;
    int d = rem / 16, j = rem % 16;
    ws[OFF_UPW + (size_t)(j*128 + e)*128 + d] = upw[i];
  }
  for (int i = tid; i < 64*128*3; i += stride) {
    int o = i / 384, r = i % 384;          // r = c*3+k
    ws[OFF_W1D + (size_t)r*64 + o] = w1d[i];
  }
  for (int j = tid; j < 1024; j += stride) {
    float s = 0.f;
    for (int d = 0; d < 128; ++d) {
      float v = em[d*1024 + j];
      ws[OFF_EMT + (size_t)j*128 + d] = v;
      s = fmaf(v, v, s);
    }
    ws[OFF_EN + j] = s;
  }
}

// ---------------- RevIN ----------------
__global__ __launch_bounds__(256) void k_revin(
    const float* __restrict__ x, const float* __restrict__ rw, const float* __restrict__ rb,
    float* __restrict__ xn)
{
  int n = blockIdx.x;            // sample = b*8 + c
  int b = n >> 3, c = n & 7;
  int t = threadIdx.x;
  const float* xp = x + (size_t)b*8192 + c;
  float v[4]; float s = 0.f, s2 = 0.f;
  #pragma unroll
  for (int i = 0; i < 4; ++i) {
    v[i] = xp[(size_t)(t + i*256)*8];
    s += v[i]; s2 = fmaf(v[i], v[i], s2);
  }
  __shared__ float sh[8];
  __shared__ float st[2];
  for (int o = 32; o; o >>= 1) { s += __shfl_down(s, o, 64); s2 += __shfl_down(s2, o, 64); }
  if ((t & 63) == 0) { sh[t >> 6] = s; sh[4 + (t >> 6)] = s2; }
  __syncthreads();
  if (t == 0) {
    float S = sh[0]+sh[1]+sh[2]+sh[3];
    float S2 = sh[4]+sh[5]+sh[6]+sh[7];
    float mu = S * (1.f/1024.f);
    float var = S2 * (1.f/1024.f) - mu*mu;
    st[0] = mu;
    st[1] = 1.f / sqrtf(var + 1e-5f);
  }
  __syncthreads();
  float mu = st[0], inv = st[1], w0 = rw[0], b0 = rb[0];
  #pragma unroll
  for (int i = 0; i < 4; ++i)
    xn[(size_t)n*1024 + t + i*256] = fmaf((v[i]-mu)*inv, w0, b0);
}

// ---------------- K12: h1a (in LDS) + conv2 + residual -> out0 ----------------
// block = (nloc 64 x tile 16), 512 thr; wave w: d-eighth d0 = 16w; lane = out col.
__global__ __launch_bounds__(512) void k_c12(
    const float* __restrict__ xn, float* __restrict__ out0,
    const float* __restrict__ w1a, const float* __restrict__ b1a,
    const float* __restrict__ w2aT, const float* __restrict__ b2a,
    const float* __restrict__ wd, const float* __restrict__ bd, int n0)
{
  constexpr int ST = 73;
  __shared__ float xs[72];
  __shared__ float h1[128*ST];
  int nloc = blockIdx.x >> 4, tile = blockIdx.x & 15;
  int n = n0 + nloc;
  int l0 = tile * 64;
  int t = threadIdx.x;
  if (t < 70) {
    int gl = l0 - 6 + t;
    xs[t] = (gl >= 0) ? xn[(size_t)n*1024 + gl] : 0.f;
  }
  __syncthreads();
  // h1a[c][j], j=0..67 <-> l = l0-4+j; x[l-2..l] = xs[j..j+2]; pad l<0 -> 0
  {
    int c = t & 127, q = t >> 7;
    float w0 = w1a[c*3+0], w1 = w1a[c*3+1], w2 = w1a[c*3+2], bb = b1a[c];
    #pragma unroll
    for (int i = 0; i < 17; ++i) {
      int j = q*17 + i;
      float v = fmaf(w0, xs[j], fmaf(w1, xs[j+1], fmaf(w2, xs[j+2], bb)));
      h1[c*ST + j] = (l0 - 4 + j >= 0) ? fmaxf(v, 0.f) : 0.f;
    }
  }
  __syncthreads();
  int lane = t & 63;
  int w = __builtin_amdgcn_readfirstlane(t >> 6);
  int d0 = w * 16;
  float acc[16];
  #pragma unroll
  for (int i = 0; i < 16; ++i) acc[i] = 0.f;
  for (int cc = 0; cc < 128; ++cc) {
    float r0 = h1[cc*ST + lane + 2];
    float r1 = h1[cc*ST + lane + 3];
    float r2 = h1[cc*ST + lane + 4];
    const float4* wp = (const float4*)(w2aT + (size_t)cc*384 + d0);
    #pragma unroll
    for (int jj = 0; jj < 4; ++jj) {
      float4 a = wp[jj], b = wp[32+jj], c4 = wp[64+jj];
      acc[jj*4+0] = fmaf(a.x, r0, fmaf(b.x, r1, fmaf(c4.x, r2, acc[jj*4+0])));
      acc[jj*4+1] = fmaf(a.y, r0, fmaf(b.y, r1, fmaf(c4.y, r2, acc[jj*4+1])));
      acc[jj*4+2] = fmaf(a.z, r0, fmaf(b.z, r1, fmaf(c4.z, r2, acc[jj*4+2])));
      acc[jj*4+3] = fmaf(a.w, r0, fmaf(b.w, r1, fmaf(c4.w, r2, acc[jj*4+3])));
    }
  }
  int l = l0 + lane;
  float xv = xn[(size_t)n*1024 + l];
  float* ob = out0 + (size_t)nloc*131072 + (size_t)d0*1024 + l;
  #pragma unroll
  for (int i = 0; i < 16; ++i) {
    int d = d0 + i;
    float o = fmaxf(fmaxf(acc[i] + b2a[d], 0.f) + fmaf(wd[d], xv, bd[d]), 0.f);
    ob[(size_t)i*1024] = o;
  }
}

// ---------------- K34: conv3 (h1b in LDS) + conv4 + residual -> out1 ----------------
// block = (nloc 64 x tile 17), tile covers 62 out cols (last 32). 512 thr.
__global__ __launch_bounds__(512) void k_c34(
    const float* __restrict__ out0, float* __restrict__ out1,
    const float* __restrict__ w1bT, const float* __restrict__ b1b,
    const float* __restrict__ w2bT, const float* __restrict__ b2b)
{
  constexpr int ST = 72;
  __shared__ float buf0[128*ST];   // staged out0, cols lb..lb+67
  __shared__ float buf1[128*ST];   // h1b, col j <-> gcol l0-2+j
  int nloc = blockIdx.x / 17, tile = blockIdx.x % 17;
  int l0 = tile * 62;
  int ncols = min(62, 1024 - l0);
  int t = threadIdx.x;
  int lb = (l0 >= 4) ? ((l0 - 4) & ~3) : -4;
  int ja = (l0 - 4) - lb;                       // 0 or 2
  const float* src = out0 + (size_t)nloc*131072;
  for (int idx = t; idx < 128*17; idx += 512) {
    int row = idx / 17, f = idx % 17;
    int gl = lb + f*4;
    float4 v = make_float4(0.f, 0.f, 0.f, 0.f);
    if (gl >= 0 && gl < 1024) v = *(const float4*)(src + (size_t)row*1024 + gl);
    float* dstp = buf0 + row*ST + f*4;
    *(float2*)dstp = make_float2(v.x, v.y);
    *(float2*)(dstp + 2) = make_float2(v.z, v.w);
  }
  __syncthreads();
  int lane = t & 63;
  int w = __builtin_amdgcn_readfirstlane(t >> 6);
  int d0 = w * 16;
  // conv3: h1b at gcol = l0-2+lane; reads out0[gcol-2..gcol] = buf0[ja+lane ..+2]
  {
    float acc[16];
    #pragma unroll
    for (int i = 0; i < 16; ++i) acc[i] = 0.f;
    int base = ja + lane;
    for (int cc = 0; cc < 128; ++cc) {
      float r0 = buf0[cc*ST + base];
      float r1 = buf0[cc*ST + base + 1];
      float r2 = buf0[cc*ST + base + 2];
      const float4* wp = (const float4*)(w1bT + (size_t)cc*384 + d0);
      #pragma unroll
      for (int jj = 0; jj < 4; ++jj) {
        float4 a = wp[jj], b = wp[32+jj], c4 = wp[64+jj];
        acc[jj*4+0] = fmaf(a.x, r0, fmaf(b.x, r1, fmaf(c4.x, r2, acc[jj*4+0])));
        acc[jj*4+1] = fmaf(a.y, r0, fmaf(b.y, r1, fmaf(c4.y, r2, acc[jj*4+1])));
        acc[jj*4+2] = fmaf(a.z, r0, fmaf(b.z, r1, fmaf(c4.z, r2, acc[jj*4+2])));
        acc[jj*4+3] = fmaf(a.w, r0, fmaf(b.w, r1, fmaf(c4.w, r2, acc[jj*4+3])));
      }
    }
    int gcol = l0 - 2 + lane;
    bool valid = (gcol >= 0) && (gcol < 1024);
    #pragma unroll
    for (int i = 0; i < 16; ++i)
      buf1[(d0+i)*ST + lane] = valid ? fmaxf(acc[i] + b1b[d0+i], 0.f) : 0.f;
  }
  __syncthreads();
  // conv4: out col l = l0+lane (lane<ncols); h1b[l-2..l] = buf1[lane..lane+2]
  {
    float acc[16];
    #pragma unroll
    for (int i = 0; i < 16; ++i) acc[i] = 0.f;
    for (int cc = 0; cc < 128; ++cc) {
      float r0 = buf1[cc*ST + lane];
      float r1 = buf1[cc*ST + lane + 1];
      float r2 = buf1[cc*ST + lane + 2];
      const float4* wp = (const float4*)(w2bT + (size_t)cc*384 + d0);
      #pragma unroll
      for (int jj = 0; jj < 4; ++jj) {
        float4 a = wp[jj], b = wp[32+jj], c4 = wp[64+jj];
        acc[jj*4+0] = fmaf(a.x, r0, fmaf(b.x, r1, fmaf(c4.x, r2, acc[jj*4+0])));
        acc[jj*4+1] = fmaf(a.y, r0, fmaf(b.y, r1, fmaf(c4.y, r2, acc[jj*4+1])));
        acc[jj*4+2] = fmaf(a.z, r0, fmaf(b.z, r1, fmaf(c4.z, r2, acc[jj*4+2])));
        acc[jj*4+3] = fmaf(a.w, r0, fmaf(b.w, r1, fmaf(c4.w, r2, acc[jj*4+3])));
      }
    }
    if (lane < ncols) {
      int rbase = ja + 4 + lane;   // buf0 idx of gcol = l0+lane
      float* ob = out1 + (size_t)nloc*131072 + (size_t)d0*1024 + l0 + lane;
      #pragma unroll
      for (int i = 0; i < 16; ++i) {
        float res = buf0[(d0+i)*ST + rbase];
        ob[(size_t)i*1024] = fmaxf(fmaxf(acc[i] + b2b[d0+i], 0.f) + res, 0.f);
      }
    }
  }
}

// ---------------- K5: patchify GEMM partial ----------------
__global__ __launch_bounds__(256) void k_pfy(
    const float* __restrict__ B, const float* __restrict__ pwT, float* __restrict__ pfp)
{
  __shared__ float as[64*64];   // [Kloc 64][p 64]
  int nloc = blockIdx.x >> 2, cq = blockIdx.x & 3;
  int t = threadIdx.x;
  int rq = t >> 4, dg = t & 15;
  float acc[4][8];
  #pragma unroll
  for (int r = 0; r < 4; ++r)
    #pragma unroll
    for (int m = 0; m < 8; ++m) acc[r][m] = 0.f;

  const float* src = B + (size_t)nloc*131072 + (size_t)cq*32*1024;
  for (int cci = 0; cci < 8; ++cci) {
    __syncthreads();
    {
      int cloc = t >> 6, p = t & 63;
      const float4* s4 = (const float4*)(src + (size_t)(cci*4 + cloc)*1024 + p*16);
      float4 v0 = s4[0], v1 = s4[1], v2 = s4[2], v3 = s4[3];
      float vv[16] = {v0.x,v0.y,v0.z,v0.w, v1.x,v1.y,v1.z,v1.w,
                      v2.x,v2.y,v2.z,v2.w, v3.x,v3.y,v3.z,v3.w};
      #pragma unroll
      for (int k = 0; k < 16; ++k) as[(cloc*16 + k)*64 + p] = vv[k];
    }
    __syncthreads();
    const float* wbase = pwT + ((size_t)(cq*32 + cci*4)*16)*128 + dg*8;
    for (int K = 0; K < 64; ++K) {
      float4 a4 = *(const float4*)(as + K*64 + rq*4);
      float4 wA = *(const float4*)(wbase + (size_t)K*128);
      float4 wB = *(const float4*)(wbase + (size_t)K*128 + 4);
      float av[4] = {a4.x, a4.y, a4.z, a4.w};
      #pragma unroll
      for (int r = 0; r < 4; ++r) {
        acc[r][0] = fmaf(av[r], wA.x, acc[r][0]);
        acc[r][1] = fmaf(av[r], wA.y, acc[r][1]);
        acc[r][2] = fmaf(av[r], wA.z, acc[r][2]);
        acc[r][3] = fmaf(av[r], wA.w, acc[r][3]);
        acc[r][4] = fmaf(av[r], wB.x, acc[r][4]);
        acc[r][5] = fmaf(av[r], wB.y, acc[r][5]);
        acc[r][6] = fmaf(av[r], wB.z, acc[r][6]);
        acc[r][7] = fmaf(av[r], wB.w, acc[r][7]);
      }
    }
  }
  #pragma unroll
  for (int r = 0; r < 4; ++r) {
    float* dst = pfp + ((size_t)cq*4096 + nloc*64 + rq*4 + r)*128 + dg*8;
    *(float4*)dst = make_float4(acc[r][0], acc[r][1], acc[r][2], acc[r][3]);
    *(float4*)(dst + 4) = make_float4(acc[r][4], acc[r][5], acc[r][6], acc[r][7]);
  }
}

// ---------------- K5r: reduce 4 K-splits + bias -> pf ----------------
__global__ __launch_bounds__(256) void k_pfred(
    const float* __restrict__ pfp, const float* __restrict__ pb,
    float* __restrict__ pf, int row0)
{
  int idx = blockIdx.x * 256 + threadIdx.x;
  size_t base = (size_t)idx * 8;
  int d = (int)(base & 127);
  float4 s0 = *(const float4*)(pfp + base);
  float4 s1 = *(const float4*)(pfp + base + 4);
  #pragma unroll
  for (int cq = 1; cq < 4; ++cq) {
    float4 a0 = *(const float4*)(pfp + (size_t)cq*524288 + base);
    float4 a1 = *(const float4*)(pfp + (size_t)cq*524288 + base + 4);
    s0.x += a0.x; s0.y += a0.y; s0.z += a0.z; s0.w += a0.w;
    s1.x += a1.x; s1.y += a1.y; s1.z += a1.z; s1.w += a1.w;
  }
  float4 b0 = *(const float4*)(pb + d);
  float4 b1 = *(const float4*)(pb + d + 4);
  s0.x += b0.x; s0.y += b0.y; s0.z += b0.z; s0.w += b0.w;
  s1.x += b1.x; s1.y += b1.y; s1.z += b1.z; s1.w += b1.w;
  float* dst = pf + (size_t)row0*128 + base;
  *(float4*)dst = s0;
  *(float4*)(dst + 4) = s1;
}

// ---------------- VQ argmin: dist' = |e|^2 - 2 f.e ----------------
__global__ __launch_bounds__(256) void k_vq(float* ws)
{
  __shared__ __align__(16) float fT[128*132];
  __shared__ __align__(16) float ech[64*128];
  __shared__ float ens[64];
  __shared__ float2 red[128*16];
  const float* pf  = ws + OFF_PF;
  const float* emT = ws + OFF_EMT;
  const float* en  = ws + OFF_EN;
  int* ind = (int*)(ws + OFF_IND);

  int t = threadIdx.x;
  int r0 = blockIdx.x * 128;
  for (int s = t; s < 16384; s += 256) {
    int rr = s >> 7, d = s & 127;
    fT[d*132 + rr] = pf[(size_t)(r0 + rr)*128 + d];
  }
  int rg = t & 15, jg = t >> 4;
  float bv[8]; int bi[8];
  #pragma unroll
  for (int r = 0; r < 8; ++r) { bv[r] = 3.4e38f; bi[r] = 0; }

  for (int ch = 0; ch < 16; ++ch) {
    __syncthreads();
    {
      const float4* src = (const float4*)(emT + (size_t)ch*8192);
      for (int q = t; q < 2048; q += 256) {
        int jj = q >> 5, dq4 = q & 31;
        *(float4*)(ech + jj*128 + ((dq4*4) ^ ((jj&7)<<2))) = src[q];
      }
      if (t < 64) ens[t] = en[ch*64 + t];
    }
    __syncthreads();
    float acc[8][4] = {};
    for (int db = 0; db < 128; db += 4) {
      float4 e0 = *(const float4*)(ech + (jg*4+0)*128 + (db ^ (((jg*4+0)&7)<<2)));
      float4 e1 = *(const float4*)(ech + (jg*4+1)*128 + (db ^ (((jg*4+1)&7)<<2)));
      float4 e2 = *(const float4*)(ech + (jg*4+2)*128 + (db ^ (((jg*4+2)&7)<<2)));
      float4 e3 = *(const float4*)(ech + (jg*4+3)*128 + (db ^ (((jg*4+3)&7)<<2)));
      #pragma unroll
      for (int u = 0; u < 4; ++u) {
        const float* fp = fT + (db+u)*132 + rg*8;
        float4 fa = *(const float4*)fp;
        float4 fb = *(const float4*)(fp + 4);
        float fv[8] = {fa.x,fa.y,fa.z,fa.w,fb.x,fb.y,fb.z,fb.w};
        float ev[4] = { ((const float*)&e0)[u], ((const float*)&e1)[u],
                        ((const float*)&e2)[u], ((const float*)&e3)[u] };
        #pragma unroll
        for (int r = 0; r < 8; ++r)
          #pragma unroll
          for (int j = 0; j < 4; ++j)
            acc[r][j] = fmaf(fv[r], ev[j], acc[r][j]);
      }
    }
    #pragma unroll
    for (int r = 0; r < 8; ++r)
      #pragma unroll
      for (int j = 0; j < 4; ++j) {
        float dist = ens[jg*4 + j] - 2.f*acc[r][j];
        int code = ch*64 + jg*4 + j;
        if (dist < bv[r]) { bv[r] = dist; bi[r] = code; }
      }
  }
  __syncthreads();
  #pragma unroll
  for (int r = 0; r < 8; ++r)
    red[(rg*8 + r)*16 + jg] = make_float2(bv[r], __int_as_float(bi[r]));
  __syncthreads();
  if (t < 128) {
    float2 v0 = red[t*16 + 0];
    float best = v0.x; int besti = __float_as_int(v0.y);
    for (int j = 1; j < 16; ++j) {
      float2 v = red[t*16 + j];
      int vi = __float_as_int(v.y);
      if (v.x < best || (v.x == best && vi < besti)) { best = v.x; besti = vi; }
    }
    ind[r0 + t] = besti;
  }
}

// ---------------- gather: z_q -> d_out, vq-loss partials ----------------
__global__ __launch_bounds__(256) void k_gather(float* ws, float* __restrict__ dout)
{
  const float* pf  = ws + OFF_PF;
  const float* emT = ws + OFF_EMT;
  const int* ind = (const int*)(ws + OFF_IND);
  float* vq_part = ws + OFF_VP;

  int t = threadIdx.x;
  int d = t & 127;
  float s = 0.f;
  #pragma unroll
  for (int it = 0; it < 4; ++it) {
    int rr = (t >> 7) + it*2;
    size_t row = (size_t)blockIdx.x*8 + rr;
    int idx = ind[row];
    float q = emT[(size_t)idx*128 + d];
    float f = pf[row*128 + d];
    float qm = q - f;
    dout[row*128 + d] = f + qm;
    s = fmaf(qm, qm, s);
  }
  __shared__ float sh[4];
  for (int o = 32; o; o >>= 1) s += __shfl_down(s, o, 64);
  if ((t & 63) == 0) sh[t >> 6] = s;
  __syncthreads();
  if (t == 0) vq_part[blockIdx.x] = sh[0]+sh[1]+sh[2]+sh[3];
}

DI float gelu_f(float x) {
  // tanh-form gelu; only affects the loss scalar (error ~1e-3 << 0.044 threshold)
  float u = x * fmaf(0.0356774081f, x*x, 0.7978845608f);
  float e = __expf(2.f * u);
  float th = 1.f - 2.f / (e + 1.f);
  return 0.5f * x * (1.f + th);
}

// ---------------- decoder: tile=64, 512 threads ----------------
__global__ __launch_bounds__(512) void k_decoder(
    const float* __restrict__ zq, float* ws,
    const float* __restrict__ upb, const float* __restrict__ db1,
    const float* __restrict__ dw2, const float* __restrict__ db2)
{
  constexpr int UPS = 70;
  constexpr int DS  = 70;
  __shared__ __align__(16) float ztT[128*8];
  __shared__ __align__(16) float up_s[128*UPS];
  __shared__ __align__(16) float dsh[64*DS];
  __shared__ __align__(16) float wd2[200];

  const float* upwT = ws + OFF_UPW;
  const float* w1dT = ws + OFF_W1D;
  const float* xn   = ws + OFF_XN;
  float* recon_part = ws + OFF_RP;

  int blk = blockIdx.x;
  int n = blk >> 4, tile = blk & 15;
  int l0 = tile*64, p0 = tile*4;
  int t = threadIdx.x;

  for (int s = t; s < 768; s += 512) {
    int e = s & 127, pi = s >> 7;
    int p = p0 - 1 + pi;
    ztT[e*8 + pi] = (p >= 0 && p < 64) ? zq[((size_t)n*64 + p)*128 + e] : 0.f;
  }
  __syncthreads();

  // phase U: thread = (jj = t>>5 in 0..15, d4 = (t&31)*4); float4 weights
  {
    int jj = t >> 5;
    int d4 = (t & 31) * 4;
    float acc[6][4] = {};
    const float* wbase = upwT + (size_t)jj*16384 + d4;
    for (int e = 0; e < 128; ++e) {
      float4 z0 = *(const float4*)(ztT + e*8);
      float2 z1 = *(const float2*)(ztT + e*8 + 4);
      float zr[6] = {z0.x, z0.y, z0.z, z0.w, z1.x, z1.y};
      float4 wv = *(const float4*)(wbase + (size_t)e*128);
      #pragma unroll
      for (int pi = 0; pi < 6; ++pi) {
        acc[pi][0] = fmaf(zr[pi], wv.x, acc[pi][0]);
        acc[pi][1] = fmaf(zr[pi], wv.y, acc[pi][1]);
        acc[pi][2] = fmaf(zr[pi], wv.z, acc[pi][2]);
        acc[pi][3] = fmaf(zr[pi], wv.w, acc[pi][3]);
      }
    }
    float ub0 = upb[d4], ub1 = upb[d4+1], ub2 = upb[d4+2], ub3 = upb[d4+3];
    #pragma unroll
    for (int pi = 0; pi < 6; ++pi) {
      int l = (p0 - 1 + pi)*16 + jj;
      int col = l - l0 + 2;
      if (col >= 0 && col < 68) {
        bool v = ((unsigned)l < 1024u);
        up_s[(d4+0)*UPS + col] = v ? acc[pi][0] + ub0 : 0.f;
        up_s[(d4+1)*UPS + col] = v ? acc[pi][1] + ub1 : 0.f;
        up_s[(d4+2)*UPS + col] = v ? acc[pi][2] + ub2 : 0.f;
        up_s[(d4+3)*UPS + col] = v ? acc[pi][3] + ub3 : 0.f;
      }
    }
  }
  __syncthreads();

  int o2 = t & 31, q = t >> 5;
  int oA = 2*o2, oB = oA + 1;
  int colb = (q == 0) ? 0 : 4*q + 2;
  int ni   = (q == 0) ? 6 : 4;
  float accA[6] = {}, accB[6] = {};
  for (int cb = 0; cb < 8; ++cb) {
    __syncthreads();
    for (int s = t; s < 3072; s += 512) dsh[s] = w1dT[(size_t)cb*3072 + s];
    __syncthreads();
    for (int cl = 0; cl < 16; ++cl) {
      int c = cb*16 + cl;
      const float* row = up_s + c*UPS + colb;
      float r[8];
      #pragma unroll
      for (int x = 0; x < 8; x += 2) { float2 v = *(const float2*)(row + x); r[x]=v.x; r[x+1]=v.y; }
      float2 w0 = *(const float2*)(dsh + (cl*3+0)*64 + oA);
      float2 w1 = *(const float2*)(dsh + (cl*3+1)*64 + oA);
      float2 w2 = *(const float2*)(dsh + (cl*3+2)*64 + oA);
      #pragma unroll
      for (int i = 0; i < 6; ++i) {
        if (i < ni) {
          accA[i] = fmaf(w0.x, r[i], fmaf(w1.x, r[i+1], fmaf(w2.x, r[i+2], accA[i])));
          accB[i] = fmaf(w0.y, r[i], fmaf(w1.y, r[i+1], fmaf(w2.y, r[i+2], accB[i])));
        }
      }
    }
  }
  __syncthreads();
  {
    float bA = db1[oA], bB = db1[oB];
    for (int i = 0; i < ni; ++i) {
      int col = colb + i;
      int l = l0 - 1 + col;
      float vA = 0.f, vB = 0.f;
      if ((unsigned)l < 1024u) {
        vA = gelu_f(accA[i] + bA);
        vB = gelu_f(accB[i] + bB);
      }
      dsh[oA*DS + col] = vA;
      dsh[oB*DS + col] = vB;
    }
  }
  if (t < 192) wd2[t] = dw2[t];
  __syncthreads();

  if (t < 256) {
    int loff = t & 63, ch = t >> 6;
    float part = 0.f;
    for (int cl = 0; cl < 16; ++cl) {
      int c = ch*16 + cl;
      part = fmaf(wd2[c*3+0], dsh[c*DS + loff],
             fmaf(wd2[c*3+1], dsh[c*DS + loff + 1],
             fmaf(wd2[c*3+2], dsh[c*DS + loff + 2], part)));
    }
    ztT[loff*4 + ch] = part;
  }
  __syncthreads();
  if (t < 64) {
    float acc = ztT[t*4+0] + ztT[t*4+1] + ztT[t*4+2] + ztT[t*4+3] + db2[0];
    float diff = acc - xn[(size_t)n*1024 + l0 + t];
    float part = diff*diff;
    for (int o = 32; o; o >>= 1) part += __shfl_down(part, o, 64);
    if (t == 0) recon_part[blk] = part;
  }
}

// ---------------- finalize loss ----------------
__global__ __launch_bounds__(256) void k_finalize(const float* __restrict__ ws, float* __restrict__ dout)
{
  const float* rp = ws + OFF_RP;
  const float* vp = ws + OFF_VP;
  int t = threadIdx.x;
  float s1 = 0.f, s2 = 0.f;
  for (int i = t; i < 8192; i += 256) s1 += rp[i];
  for (int i = t; i < 4096; i += 256) s2 += vp[i];
  __shared__ float sh[8];
  for (int o = 32; o; o >>= 1) { s1 += __shfl_down(s1,o,64); s2 += __shfl_down(s2,o,64); }
  if ((t & 63) == 0) { sh[t >> 6] = s1; sh[4 + (t >> 6)] = s2; }
  __syncthreads();
  if (t == 0) {
    float R = sh[0]+sh[1]+sh[2]+sh[3];
    float V = sh[4]+sh[5]+sh[6]+sh[7];
    dout[4194304] = R * (1.f/524288.f) + 0.25f * (V * (1.f/4194304.f));
  }
}

// ---------------- host ----------------
extern "C" void kernel_launch(void* const* d_in, const int* in_sizes, int n_in,
                              void* d_out, int out_size, void* d_ws, size_t ws_size,
                              hipStream_t stream)
{
  const float* x    = (const float*)d_in[0];
  const float* rw   = (const float*)d_in[1];
  const float* rb   = (const float*)d_in[2];
  const float* w1a  = (const float*)d_in[3];
  const float* b1a  = (const float*)d_in[4];
  const float* w2a  = (const float*)d_in[5];
  const float* b2a  = (const float*)d_in[6];
  const float* wda  = (const float*)d_in[7];
  const float* bda  = (const float*)d_in[8];
  const float* w1b  = (const float*)d_in[9];
  const float* b1b  = (const float*)d_in[10];
  const float* w2b  = (const float*)d_in[11];
  const float* b2b  = (const float*)d_in[12];
  const float* pw   = (const float*)d_in[13];
  const float* pb   = (const float*)d_in[14];
  const float* em   = (const float*)d_in[15];
  const float* upw  = (const float*)d_in[16];
  const float* upb  = (const float*)d_in[17];
  const float* dw1  = (const float*)d_in[18];
  const float* db1  = (const float*)d_in[19];
  const float* dw2  = (const float*)d_in[20];
  const float* db2  = (const float*)d_in[21];
  float* ws = (float*)d_ws;
  float* out = (float*)d_out;

  float* xn   = ws + OFF_XN;
  float* A    = ws + OFF_A;          // out1
  float* B    = ws + OFF_B;          // out0; reused as pfp after k_c34
  float* pf   = ws + OFF_PF;
  const float* w2aT = ws + OFF_W2A;
  const float* w1bT = ws + OFF_W1B;
  const float* w2bT = ws + OFF_W2B;
  const float* pwT  = ws + OFF_PW;

  k_prep<<<256, 256, 0, stream>>>(w2a, w1b, w2b, pw, upw, dw1, em, ws);
  k_revin<<<512, 256, 0, stream>>>(x, rw, rb, xn);
  for (int nc = 0; nc < 8; ++nc) {
    int n0 = nc * 64;
    k_c12<<<1024, 512, 0, stream>>>(xn, B, w1a, b1a, w2aT, b2a, wda, bda, n0);
    k_c34<<<1088, 512, 0, stream>>>(B, A, w1bT, b1b, w2bT, b2b);
    k_pfy<<<256, 256, 0, stream>>>(A, pwT, B);           // pfp aliases B (out0 dead)
    k_pfred<<<256, 256, 0, stream>>>(B, pb, pf, nc*4096);
  }
  k_vq<<<256, 256, 0, stream>>>(ws);
  k_gather<<<4096, 256, 0, stream>>>(ws, out);
  k_decoder<<<8192, 512, 0, stream>>>(out, ws, upb, db1, dw2, db2);
  k_finalize<<<1, 256, 0, stream>>>(ws, out);
}

// Round 7
// 3484.309 us; speedup vs baseline: 1.7517x; 1.2728x over previous
//
#include <hip/hip_runtime.h>

// ---------------- workspace layout (floats) ----------------
constexpr size_t OFF_XN  = 0;                      // 512*1024
constexpr size_t OFF_PF  = 524288;                 // 32768*128
constexpr size_t OFF_W2A = OFF_PF  + 4194304;      // [(cc*3+k)*128+d]
constexpr size_t OFF_W1B = OFF_W2A + 49152;
constexpr size_t OFF_W2B = OFF_W1B + 49152;
constexpr size_t OFF_PW  = OFF_W2B + 49152;        // [(c*16+k)*128+d]
constexpr size_t OFF_UPW = OFF_PW  + 262144;       // [(j*128+e)*128+d]
constexpr size_t OFF_W1D = OFF_UPW + 262144;       // [(c*3+k)*64+o]
constexpr size_t OFF_EMT = OFF_W1D + 24576;        // [j*128+d]
constexpr size_t OFF_EN  = OFF_EMT + 131072;       // 1024
constexpr size_t OFF_RP  = OFF_EN  + 1024;         // 8192
constexpr size_t OFF_VP  = OFF_RP  + 8192;         // 4096
constexpr size_t OFF_IND = OFF_VP  + 4096;         // 32768 int
// total ~21.7 MB

#define DI __device__ __forceinline__

// ---------------- prep: weight transposes + embedT + |e|^2 ----------------
__global__ __launch_bounds__(256) void k_prep(
    const float* __restrict__ w2a, const float* __restrict__ w1b, const float* __restrict__ w2b,
    const float* __restrict__ pw,  const float* __restrict__ upw, const float* __restrict__ w1d,
    const float* __restrict__ em,  float* __restrict__ ws)
{
  int tid = blockIdx.x * 256 + threadIdx.x;
  int stride = gridDim.x * 256;
  for (int i = tid; i < 128*128*3; i += stride) {
    int d = i / 384, r = i % 384;          // r = cc*3+k
    ws[OFF_W2A + (size_t)r*128 + d] = w2a[i];
    ws[OFF_W1B + (size_t)r*128 + d] = w1b[i];
    ws[OFF_W2B + (size_t)r*128 + d] = w2b[i];
  }
  for (int i = tid; i < 128*128*16; i += stride) {
    int d = i / 2048, r = i % 2048;        // r = c*16+k
    ws[OFF_PW + (size_t)r*128 + d] = pw[i];
  }
  for (int i = tid; i < 128*128*16; i += stride) {
    int e = i / 2048, rem = i % 2048;
    int d = rem / 16, j = rem % 16;
    ws[OFF_UPW + (size_t)(j*128 + e)*128 + d] = upw[i];
  }
  for (int i = tid; i < 64*128*3; i += stride) {
    int o = i / 384, r = i % 384;          // r = c*3+k
    ws[OFF_W1D + (size_t)r*64 + o] = w1d[i];
  }
  for (int j = tid; j < 1024; j += stride) {
    float s = 0.f;
    for (int d = 0; d < 128; ++d) {
      float v = em[d*1024 + j];
      ws[OFF_EMT + (size_t)j*128 + d] = v;
      s = fmaf(v, v, s);
    }
    ws[OFF_EN + j] = s;
  }
}

// ---------------- RevIN ----------------
__global__ __launch_bounds__(256) void k_revin(
    const float* __restrict__ x, const float* __restrict__ rw, const float* __restrict__ rb,
    float* __restrict__ xn)
{
  int n = blockIdx.x;            // sample = b*8 + c
  int b = n >> 3, c = n & 7;
  int t = threadIdx.x;
  const float* xp = x + (size_t)b*8192 + c;
  float v[4]; float s = 0.f, s2 = 0.f;
  #pragma unroll
  for (int i = 0; i < 4; ++i) {
    v[i] = xp[(size_t)(t + i*256)*8];
    s += v[i]; s2 = fmaf(v[i], v[i], s2);
  }
  __shared__ float sh[8];
  __shared__ float st[2];
  for (int o = 32; o; o >>= 1) { s += __shfl_down(s, o, 64); s2 += __shfl_down(s2, o, 64); }
  if ((t & 63) == 0) { sh[t >> 6] = s; sh[4 + (t >> 6)] = s2; }
  __syncthreads();
  if (t == 0) {
    float S = sh[0]+sh[1]+sh[2]+sh[3];
    float S2 = sh[4]+sh[5]+sh[6]+sh[7];
    float mu = S * (1.f/1024.f);
    float var = S2 * (1.f/1024.f) - mu*mu;
    st[0] = mu;
    st[1] = 1.f / sqrtf(var + 1e-5f);
  }
  __syncthreads();
  float mu = st[0], inv = st[1], w0 = rw[0], b0 = rb[0];
  #pragma unroll
  for (int i = 0; i < 4; ++i)
    xn[(size_t)n*1024 + t + i*256] = fmaf((v[i]-mu)*inv, w0, b0);
}

// ---------------- fully fused encoder: h1a->out0->h1b->out1->patchify, all in LDS ----
// block = (n, tile of 64 cols). 512 thr, 8 waves; wave w owns d-slice; lane = col.
// bufA [64][70]: h1a half (cc-split) / h1b half (d-split) / patchify partials.
// bufB [128][68]: out0 (cols l0-4..l0+63) -> out1 (cols l0..l0+63).
constexpr int STA = 70;
constexpr int STB = 68;

__global__ __launch_bounds__(512) void k_enc(
    const float* __restrict__ xn, float* __restrict__ pf,
    const float* __restrict__ w1a, const float* __restrict__ b1a,
    const float* __restrict__ w2aT, const float* __restrict__ b2a,
    const float* __restrict__ wd,  const float* __restrict__ bd,
    const float* __restrict__ w1bT, const float* __restrict__ b1b,
    const float* __restrict__ w2bT, const float* __restrict__ b2b,
    const float* __restrict__ pwT, const float* __restrict__ pb)
{
  __shared__ float xs[72];
  __shared__ __align__(16) float bufA[64*STA];
  __shared__ __align__(16) float bufB[128*STB];
  int n = blockIdx.x >> 4, tile = blockIdx.x & 15;
  int l0 = tile * 64;
  int t = threadIdx.x;
  int lane = t & 63;
  int w = __builtin_amdgcn_readfirstlane(t >> 6);
  int d0 = w * 16;

  if (t < 72) {
    int gl = l0 - 8 + t;
    xs[t] = (gl >= 0) ? xn[(size_t)n*1024 + gl] : 0.f;
  }
  __syncthreads();

  float acc2[16];
  #pragma unroll
  for (int i = 0; i < 16; ++i) acc2[i] = 0.f;
  float hacc[4] = {0.f, 0.f, 0.f, 0.f};

  // ---- h1a (cc halves) + conv2 accumulation ----
  for (int rep = 0; rep < 2; ++rep) {
    {                                   // h1a rows rep*64..+63, cols j<70 <-> l = l0-6+j
      int row = t & 63, colg = t >> 6;
      int c = rep*64 + row;
      float w0 = w1a[c*3+0], w1 = w1a[c*3+1], w2 = w1a[c*3+2], bb = b1a[c];
      #pragma unroll
      for (int i = 0; i < 9; ++i) {
        int j = colg*9 + i;
        if (j < 70) {
          float v = fmaf(w0, xs[j], fmaf(w1, xs[j+1], fmaf(w2, xs[j+2], bb)));
          bufA[row*STA + j] = (l0 - 6 + j >= 0) ? fmaxf(v, 0.f) : 0.f;
        }
      }
    }
    __syncthreads();
    for (int cc2 = 0; cc2 < 64; ++cc2) {   // conv2 main: out0 col l = l0+lane
      float r0 = bufA[cc2*STA + lane + 4];
      float r1 = bufA[cc2*STA + lane + 5];
      float r2 = bufA[cc2*STA + lane + 6];
      const float4* wp = (const float4*)(w2aT + (size_t)(rep*64 + cc2)*384 + d0);
      #pragma unroll
      for (int jj = 0; jj < 4; ++jj) {
        float4 a = wp[jj], b = wp[32+jj], c4 = wp[64+jj];
        acc2[jj*4+0] = fmaf(a.x, r0, fmaf(b.x, r1, fmaf(c4.x, r2, acc2[jj*4+0])));
        acc2[jj*4+1] = fmaf(a.y, r0, fmaf(b.y, r1, fmaf(c4.y, r2, acc2[jj*4+1])));
        acc2[jj*4+2] = fmaf(a.z, r0, fmaf(b.z, r1, fmaf(c4.z, r2, acc2[jj*4+2])));
        acc2[jj*4+3] = fmaf(a.w, r0, fmaf(b.w, r1, fmaf(c4.w, r2, acc2[jj*4+3])));
      }
    }
    if (t < 128) {                         // conv2 halo: out0 cols l0-4..l0-1, d = t
      for (int cc2 = 0; cc2 < 64; ++cc2) {
        const float* wp = w2aT + (size_t)(rep*64 + cc2)*384 + t;
        float w0 = wp[0], w1 = wp[128], w2 = wp[256];
        float q0 = bufA[cc2*STA+0], q1 = bufA[cc2*STA+1], q2 = bufA[cc2*STA+2],
              q3 = bufA[cc2*STA+3], q4 = bufA[cc2*STA+4], q5 = bufA[cc2*STA+5];
        hacc[0] = fmaf(w0, q0, fmaf(w1, q1, fmaf(w2, q2, hacc[0])));
        hacc[1] = fmaf(w0, q1, fmaf(w1, q2, fmaf(w2, q3, hacc[1])));
        hacc[2] = fmaf(w0, q2, fmaf(w1, q3, fmaf(w2, q4, hacc[2])));
        hacc[3] = fmaf(w0, q3, fmaf(w1, q4, fmaf(w2, q5, hacc[3])));
      }
    }
    __syncthreads();
  }

  // ---- out0 epilogue -> bufB (col j <-> l = l0-4+j) ----
  {
    float xv = xs[lane + 8];
    #pragma unroll
    for (int i = 0; i < 16; ++i) {
      int d = d0 + i;
      bufB[d*STB + lane + 4] =
        fmaxf(fmaxf(acc2[i] + b2a[d], 0.f) + fmaf(wd[d], xv, bd[d]), 0.f);
    }
    if (t < 128) {
      #pragma unroll
      for (int h = 0; h < 4; ++h) {
        int l = l0 - 4 + h;
        float o = 0.f;
        if (l >= 0)
          o = fmaxf(fmaxf(hacc[h] + b2a[t], 0.f) + fmaf(wd[t], xs[h+4], bd[t]), 0.f);
        bufB[t*STB + h] = o;
      }
    }
  }
  __syncthreads();

  // ---- conv3 (h1b, d-halves into bufA) + conv4 accumulation ----
  float acc4[16];
  #pragma unroll
  for (int i = 0; i < 16; ++i) acc4[i] = 0.f;
  for (int rep = 0; rep < 2; ++rep) {
    {                                     // conv3 main: h1b rows d = rep*64 + w*8 + i, col l = l0-2+lane
      float acc3[8];
      #pragma unroll
      for (int i = 0; i < 8; ++i) acc3[i] = 0.f;
      int dh = rep*64 + w*8;
      for (int cc = 0; cc < 128; ++cc) {
        float r0 = bufB[cc*STB + lane];
        float r1 = bufB[cc*STB + lane + 1];
        float r2 = bufB[cc*STB + lane + 2];
        const float4* wp = (const float4*)(w1bT + (size_t)cc*384 + dh);
        float4 a0 = wp[0],  a1 = wp[1];
        float4 b0 = wp[32], b1 = wp[33];
        float4 c0 = wp[64], c1 = wp[65];
        acc3[0] = fmaf(a0.x, r0, fmaf(b0.x, r1, fmaf(c0.x, r2, acc3[0])));
        acc3[1] = fmaf(a0.y, r0, fmaf(b0.y, r1, fmaf(c0.y, r2, acc3[1])));
        acc3[2] = fmaf(a0.z, r0, fmaf(b0.z, r1, fmaf(c0.z, r2, acc3[2])));
        acc3[3] = fmaf(a0.w, r0, fmaf(b0.w, r1, fmaf(c0.w, r2, acc3[3])));
        acc3[4] = fmaf(a1.x, r0, fmaf(b1.x, r1, fmaf(c1.x, r2, acc3[4])));
        acc3[5] = fmaf(a1.y, r0, fmaf(b1.y, r1, fmaf(c1.y, r2, acc3[5])));
        acc3[6] = fmaf(a1.z, r0, fmaf(b1.z, r1, fmaf(c1.z, r2, acc3[6])));
        acc3[7] = fmaf(a1.w, r0, fmaf(b1.w, r1, fmaf(c1.w, r2, acc3[7])));
      }
      bool valid = (l0 - 2 + lane >= 0);
      #pragma unroll
      for (int i = 0; i < 8; ++i)
        bufA[(w*8+i)*STA + lane] = valid ? fmaxf(acc3[i] + b1b[dh+i], 0.f) : 0.f;
      if (t < 64) {                       // conv3 halo: cols jbA=64,65 (gcol = l0+62,63), row t
        int d = rep*64 + t;
        float h0 = 0.f, h1v = 0.f;
        for (int cc = 0; cc < 128; ++cc) {
          const float* wp = w1bT + (size_t)cc*384 + d;
          float w0 = wp[0], w1 = wp[128], w2 = wp[256];
          // out0 jb = l - (l0-4): gcol=l0+62 needs jb 64,65,66; gcol=l0+63 needs jb 65,66,67
          float q0 = bufB[cc*STB + 64], q1 = bufB[cc*STB + 65],
                q2 = bufB[cc*STB + 66], q3 = bufB[cc*STB + 67];
          h0  = fmaf(w0, q0, fmaf(w1, q1, fmaf(w2, q2, h0)));
          h1v = fmaf(w0, q1, fmaf(w1, q2, fmaf(w2, q3, h1v)));
        }
        bufA[t*STA + 64] = fmaxf(h0  + b1b[d], 0.f);
        bufA[t*STA + 65] = fmaxf(h1v + b1b[d], 0.f);
      }
    }
    __syncthreads();
    for (int row = 0; row < 64; ++row) {  // conv4 partial: out1 col l = l0+lane
      float r0 = bufA[row*STA + lane];
      float r1 = bufA[row*STA + lane + 1];
      float r2 = bufA[row*STA + lane + 2];
      const float4* wp = (const float4*)(w2bT + (size_t)(rep*64 + row)*384 + d0);
      #pragma unroll
      for (int jj = 0; jj < 4; ++jj) {
        float4 a = wp[jj], b = wp[32+jj], c4 = wp[64+jj];
        acc4[jj*4+0] = fmaf(a.x, r0, fmaf(b.x, r1, fmaf(c4.x, r2, acc4[jj*4+0])));
        acc4[jj*4+1] = fmaf(a.y, r0, fmaf(b.y, r1, fmaf(c4.y, r2, acc4[jj*4+1])));
        acc4[jj*4+2] = fmaf(a.z, r0, fmaf(b.z, r1, fmaf(c4.z, r2, acc4[jj*4+2])));
        acc4[jj*4+3] = fmaf(a.w, r0, fmaf(b.w, r1, fmaf(c4.w, r2, acc4[jj*4+3])));
      }
    }
    __syncthreads();
  }

  // ---- out1 epilogue (residual from bufB) -> bufB cols 0..63 ----
  {
    float o1[16];
    #pragma unroll
    for (int i = 0; i < 16; ++i) {
      float res = bufB[(d0+i)*STB + lane + 4];
      o1[i] = fmaxf(fmaxf(acc4[i] + b2b[d0+i], 0.f) + res, 0.f);
    }
    __syncthreads();
    #pragma unroll
    for (int i = 0; i < 16; ++i) bufB[(d0+i)*STB + lane] = o1[i];
  }
  __syncthreads();

  // ---- patchify: thread = (cq = t>>7, dd = t&127); partials -> bufA; reduce -> pf ----
  {
    int cq = t >> 7, dd = t & 127;
    float accp[4] = {0.f, 0.f, 0.f, 0.f};
    for (int cl = 0; cl < 32; ++cl) {
      int c = cq*32 + cl;
      const float* row = bufB + c*STB;
      const float* wrow = pwT + (size_t)c*2048 + dd;
      float wv[16];
      #pragma unroll
      for (int k = 0; k < 16; ++k) wv[k] = wrow[(size_t)k*128];
      #pragma unroll
      for (int p = 0; p < 4; ++p) {
        float4 a0 = *(const float4*)(row + p*16);
        float4 a1 = *(const float4*)(row + p*16 + 4);
        float4 a2 = *(const float4*)(row + p*16 + 8);
        float4 a3 = *(const float4*)(row + p*16 + 12);
        accp[p] = fmaf(a0.x, wv[0],  accp[p]);
        accp[p] = fmaf(a0.y, wv[1],  accp[p]);
        accp[p] = fmaf(a0.z, wv[2],  accp[p]);
        accp[p] = fmaf(a0.w, wv[3],  accp[p]);
        accp[p] = fmaf(a1.x, wv[4],  accp[p]);
        accp[p] = fmaf(a1.y, wv[5],  accp[p]);
        accp[p] = fmaf(a1.z, wv[6],  accp[p]);
        accp[p] = fmaf(a1.w, wv[7],  accp[p]);
        accp[p] = fmaf(a2.x, wv[8],  accp[p]);
        accp[p] = fmaf(a2.y, wv[9],  accp[p]);
        accp[p] = fmaf(a2.z, wv[10], accp[p]);
        accp[p] = fmaf(a2.w, wv[11], accp[p]);
        accp[p] = fmaf(a3.x, wv[12], accp[p]);
        accp[p] = fmaf(a3.y, wv[13], accp[p]);
        accp[p] = fmaf(a3.z, wv[14], accp[p]);
        accp[p] = fmaf(a3.w, wv[15], accp[p]);
      }
    }
    #pragma unroll
    for (int p = 0; p < 4; ++p) bufA[(cq*4 + p)*128 + dd] = accp[p];
  }
  __syncthreads();
  {
    int p = t >> 7, dd = t & 127;
    float s = bufA[p*128 + dd];
    s += bufA[(4 + p)*128 + dd];
    s += bufA[(8 + p)*128 + dd];
    s += bufA[(12 + p)*128 + dd];
    pf[((size_t)n*64 + tile*4 + p)*128 + dd] = s + pb[dd];
  }
}

// ---------------- VQ argmin: dist' = |e|^2 - 2 f.e ----------------
__global__ __launch_bounds__(256) void k_vq(float* ws)
{
  __shared__ __align__(16) float fT[128*132];
  __shared__ __align__(16) float ech[64*128];
  __shared__ float ens[64];
  __shared__ float2 red[128*16];
  const float* pf  = ws + OFF_PF;
  const float* emT = ws + OFF_EMT;
  const float* en  = ws + OFF_EN;
  int* ind = (int*)(ws + OFF_IND);

  int t = threadIdx.x;
  int r0 = blockIdx.x * 128;
  for (int s = t; s < 16384; s += 256) {
    int rr = s >> 7, d = s & 127;
    fT[d*132 + rr] = pf[(size_t)(r0 + rr)*128 + d];
  }
  int rg = t & 15, jg = t >> 4;
  float bv[8]; int bi[8];
  #pragma unroll
  for (int r = 0; r < 8; ++r) { bv[r] = 3.4e38f; bi[r] = 0; }

  for (int ch = 0; ch < 16; ++ch) {
    __syncthreads();
    {
      const float4* src = (const float4*)(emT + (size_t)ch*8192);
      for (int q = t; q < 2048; q += 256) {
        int jj = q >> 5, dq4 = q & 31;
        *(float4*)(ech + jj*128 + ((dq4*4) ^ ((jj&7)<<2))) = src[q];
      }
      if (t < 64) ens[t] = en[ch*64 + t];
    }
    __syncthreads();
    float acc[8][4] = {};
    for (int db = 0; db < 128; db += 4) {
      float4 e0 = *(const float4*)(ech + (jg*4+0)*128 + (db ^ (((jg*4+0)&7)<<2)));
      float4 e1 = *(const float4*)(ech + (jg*4+1)*128 + (db ^ (((jg*4+1)&7)<<2)));
      float4 e2 = *(const float4*)(ech + (jg*4+2)*128 + (db ^ (((jg*4+2)&7)<<2)));
      float4 e3 = *(const float4*)(ech + (jg*4+3)*128 + (db ^ (((jg*4+3)&7)<<2)));
      #pragma unroll
      for (int u = 0; u < 4; ++u) {
        const float* fp = fT + (db+u)*132 + rg*8;
        float4 fa = *(const float4*)fp;
        float4 fb = *(const float4*)(fp + 4);
        float fv[8] = {fa.x,fa.y,fa.z,fa.w,fb.x,fb.y,fb.z,fb.w};
        float ev[4] = { ((const float*)&e0)[u], ((const float*)&e1)[u],
                        ((const float*)&e2)[u], ((const float*)&e3)[u] };
        #pragma unroll
        for (int r = 0; r < 8; ++r)
          #pragma unroll
          for (int j = 0; j < 4; ++j)
            acc[r][j] = fmaf(fv[r], ev[j], acc[r][j]);
      }
    }
    #pragma unroll
    for (int r = 0; r < 8; ++r)
      #pragma unroll
      for (int j = 0; j < 4; ++j) {
        float dist = ens[jg*4 + j] - 2.f*acc[r][j];
        int code = ch*64 + jg*4 + j;
        if (dist < bv[r]) { bv[r] = dist; bi[r] = code; }
      }
  }
  __syncthreads();
  #pragma unroll
  for (int r = 0; r < 8; ++r)
    red[(rg*8 + r)*16 + jg] = make_float2(bv[r], __int_as_float(bi[r]));
  __syncthreads();
  if (t < 128) {
    float2 v0 = red[t*16 + 0];
    float best = v0.x; int besti = __float_as_int(v0.y);
    for (int j = 1; j < 16; ++j) {
      float2 v = red[t*16 + j];
      int vi = __float_as_int(v.y);
      if (v.x < best || (v.x == best && vi < besti)) { best = v.x; besti = vi; }
    }
    ind[r0 + t] = besti;
  }
}

// ---------------- gather: z_q -> d_out, vq-loss partials ----------------
__global__ __launch_bounds__(256) void k_gather(float* ws, float* __restrict__ dout)
{
  const float* pf  = ws + OFF_PF;
  const float* emT = ws + OFF_EMT;
  const int* ind = (const int*)(ws + OFF_IND);
  float* vq_part = ws + OFF_VP;

  int t = threadIdx.x;
  int d = t & 127;
  float s = 0.f;
  #pragma unroll
  for (int it = 0; it < 4; ++it) {
    int rr = (t >> 7) + it*2;
    size_t row = (size_t)blockIdx.x*8 + rr;
    int idx = ind[row];
    float q = emT[(size_t)idx*128 + d];
    float f = pf[row*128 + d];
    float qm = q - f;
    dout[row*128 + d] = f + qm;
    s = fmaf(qm, qm, s);
  }
  __shared__ float sh[4];
  for (int o = 32; o; o >>= 1) s += __shfl_down(s, o, 64);
  if ((t & 63) == 0) sh[t >> 6] = s;
  __syncthreads();
  if (t == 0) vq_part[blockIdx.x] = sh[0]+sh[1]+sh[2]+sh[3];
}

DI float gelu_f(float x) {
  float u = x * fmaf(0.0356774081f, x*x, 0.7978845608f);
  float e = __expf(2.f * u);
  float th = 1.f - 2.f / (e + 1.f);
  return 0.5f * x * (1.f + th);
}

// ---------------- decoder: tile=64, 512 threads ----------------
__global__ __launch_bounds__(512) void k_decoder(
    const float* __restrict__ zq, float* ws,
    const float* __restrict__ upb, const float* __restrict__ db1,
    const float* __restrict__ dw2, const float* __restrict__ db2)
{
  constexpr int UPS = 70;
  constexpr int DS  = 70;
  __shared__ __align__(16) float ztT[128*8];
  __shared__ __align__(16) float up_s[128*UPS];
  __shared__ __align__(16) float dsh[64*DS];
  __shared__ __align__(16) float wd2[200];

  const float* upwT = ws + OFF_UPW;
  const float* w1dT = ws + OFF_W1D;
  const float* xn   = ws + OFF_XN;
  float* recon_part = ws + OFF_RP;

  int blk = blockIdx.x;
  int n = blk >> 4, tile = blk & 15;
  int l0 = tile*64, p0 = tile*4;
  int t = threadIdx.x;

  for (int s = t; s < 768; s += 512) {
    int e = s & 127, pi = s >> 7;
    int p = p0 - 1 + pi;
    ztT[e*8 + pi] = (p >= 0 && p < 64) ? zq[((size_t)n*64 + p)*128 + e] : 0.f;
  }
  __syncthreads();

  {
    int jj = t >> 5;
    int d4 = (t & 31) * 4;
    float acc[6][4] = {};
    const float* wbase = upwT + (size_t)jj*16384 + d4;
    for (int e = 0; e < 128; ++e) {
      float4 z0 = *(const float4*)(ztT + e*8);
      float2 z1 = *(const float2*)(ztT + e*8 + 4);
      float zr[6] = {z0.x, z0.y, z0.z, z0.w, z1.x, z1.y};
      float4 wv = *(const float4*)(wbase + (size_t)e*128);
      #pragma unroll
      for (int pi = 0; pi < 6; ++pi) {
        acc[pi][0] = fmaf(zr[pi], wv.x, acc[pi][0]);
        acc[pi][1] = fmaf(zr[pi], wv.y, acc[pi][1]);
        acc[pi][2] = fmaf(zr[pi], wv.z, acc[pi][2]);
        acc[pi][3] = fmaf(zr[pi], wv.w, acc[pi][3]);
      }
    }
    float ub0 = upb[d4], ub1 = upb[d4+1], ub2 = upb[d4+2], ub3 = upb[d4+3];
    #pragma unroll
    for (int pi = 0; pi < 6; ++pi) {
      int l = (p0 - 1 + pi)*16 + jj;
      int col = l - l0 + 2;
      if (col >= 0 && col < 68) {
        bool v = ((unsigned)l < 1024u);
        up_s[(d4+0)*UPS + col] = v ? acc[pi][0] + ub0 : 0.f;
        up_s[(d4+1)*UPS + col] = v ? acc[pi][1] + ub1 : 0.f;
        up_s[(d4+2)*UPS + col] = v ? acc[pi][2] + ub2 : 0.f;
        up_s[(d4+3)*UPS + col] = v ? acc[pi][3] + ub3 : 0.f;
      }
    }
  }
  __syncthreads();

  int o2 = t & 31, q = t >> 5;
  int oA = 2*o2, oB = oA + 1;
  int colb = (q == 0) ? 0 : 4*q + 2;
  int ni   = (q == 0) ? 6 : 4;
  float accA[6] = {}, accB[6] = {};
  for (int cb = 0; cb < 8; ++cb) {
    __syncthreads();
    for (int s = t; s < 3072; s += 512) dsh[s] = w1dT[(size_t)cb*3072 + s];
    __syncthreads();
    for (int cl = 0; cl < 16; ++cl) {
      int c = cb*16 + cl;
      const float* row = up_s + c*UPS + colb;
      float r[8];
      #pragma unroll
      for (int x = 0; x < 8; x += 2) { float2 v = *(const float2*)(row + x); r[x]=v.x; r[x+1]=v.y; }
      float2 w0 = *(const float2*)(dsh + (cl*3+0)*64 + oA);
      float2 w1 = *(const float2*)(dsh + (cl*3+1)*64 + oA);
      float2 w2 = *(const float2*)(dsh + (cl*3+2)*64 + oA);
      #pragma unroll
      for (int i = 0; i < 6; ++i) {
        if (i < ni) {
          accA[i] = fmaf(w0.x, r[i], fmaf(w1.x, r[i+1], fmaf(w2.x, r[i+2], accA[i])));
          accB[i] = fmaf(w0.y, r[i], fmaf(w1.y, r[i+1], fmaf(w2.y, r[i+2], accB[i])));
        }
      }
    }
  }
  __syncthreads();
  {
    float bA = db1[oA], bB = db1[oB];
    for (int i = 0; i < ni; ++i) {
      int col = colb + i;
      int l = l0 - 1 + col;
      float vA = 0.f, vB = 0.f;
      if ((unsigned)l < 1024u) {
        vA = gelu_f(accA[i] + bA);
        vB = gelu_f(accB[i] + bB);
      }
      dsh[oA*DS + col] = vA;
      dsh[oB*DS + col] = vB;
    }
  }
  if (t < 192) wd2[t] = dw2[t];
  __syncthreads();

  if (t < 256) {
    int loff = t & 63, ch = t >> 6;
    float part = 0.f;
    for (int cl = 0; cl < 16; ++cl) {
      int c = ch*16 + cl;
      part = fmaf(wd2[c*3+0], dsh[c*DS + loff],
             fmaf(wd2[c*3+1], dsh[c*DS + loff + 1],
             fmaf(wd2[c*3+2], dsh[c*DS + loff + 2], part)));
    }
    ztT[loff*4 + ch] = part;
  }
  __syncthreads();
  if (t < 64) {
    float acc = ztT[t*4+0] + ztT[t*4+1] + ztT[t*4+2] + ztT[t*4+3] + db2[0];
    float diff = acc - xn[(size_t)n*1024 + l0 + t];
    float part = diff*diff;
    for (int o = 32; o; o >>= 1) part += __shfl_down(part, o, 64);
    if (t == 0) recon_part[blk] = part;
  }
}

// ---------------- finalize loss ----------------
__global__ __launch_bounds__(256) void k_finalize(const float* __restrict__ ws, float* __restrict__ dout)
{
  const float* rp = ws + OFF_RP;
  const float* vp = ws + OFF_VP;
  int t = threadIdx.x;
  float s1 = 0.f, s2 = 0.f;
  for (int i = t; i < 8192; i += 256) s1 += rp[i];
  for (int i = t; i < 4096; i += 256) s2 += vp[i];
  __shared__ float sh[8];
  for (int o = 32; o; o >>= 1) { s1 += __shfl_down(s1,o,64); s2 += __shfl_down(s2,o,64); }
  if ((t & 63) == 0) { sh[t >> 6] = s1; sh[4 + (t >> 6)] = s2; }
  __syncthreads();
  if (t == 0) {
    float R = sh[0]+sh[1]+sh[2]+sh[3];
    float V = sh[4]+sh[5]+sh[6]+sh[7];
    dout[4194304] = R * (1.f/524288.f) + 0.25f * (V * (1.f/4194304.f));
  }
}

// ---------------- host ----------------
extern "C" void kernel_launch(void* const* d_in, const int* in_sizes, int n_in,
                              void* d_out, int out_size, void* d_ws, size_t ws_size,
                              hipStream_t stream)
{
  const float* x    = (const float*)d_in[0];
  const float* rw   = (const float*)d_in[1];
  const float* rb   = (const float*)d_in[2];
  const float* w1a  = (const float*)d_in[3];
  const float* b1a  = (const float*)d_in[4];
  const float* w2a  = (const float*)d_in[5];
  const float* b2a  = (const float*)d_in[6];
  const float* wda  = (const float*)d_in[7];
  const float* bda  = (const float*)d_in[8];
  const float* w1b  = (const float*)d_in[9];
  const float* b1b  = (const float*)d_in[10];
  const float* w2b  = (const float*)d_in[11];
  const float* b2b  = (const float*)d_in[12];
  const float* pw   = (const float*)d_in[13];
  const float* pb   = (const float*)d_in[14];
  const float* em   = (const float*)d_in[15];
  const float* upw  = (const float*)d_in[16];
  const float* upb  = (const float*)d_in[17];
  const float* dw1  = (const float*)d_in[18];
  const float* db1  = (const float*)d_in[19];
  const float* dw2  = (const float*)d_in[20];
  const float* db2  = (const float*)d_in[21];
  float* ws = (float*)d_ws;
  float* out = (float*)d_out;

  float* xn = ws + OFF_XN;
  float* pf = ws + OFF_PF;
  const float* w2aT = ws + OFF_W2A;
  const float* w1bT = ws + OFF_W1B;
  const float* w2bT = ws + OFF_W2B;
  const float* pwT  = ws + OFF_PW;

  k_prep<<<256, 256, 0, stream>>>(w2a, w1b, w2b, pw, upw, dw1, em, ws);
  k_revin<<<512, 256, 0, stream>>>(x, rw, rb, xn);
  k_enc<<<8192, 512, 0, stream>>>(xn, pf, w1a, b1a, w2aT, b2a, wda, bda,
                                  w1bT, b1b, w2bT, b2b, pwT, pb);
  k_vq<<<256, 256, 0, stream>>>(ws);
  k_gather<<<4096, 256, 0, stream>>>(ws, out);
  k_decoder<<<8192, 512, 0, stream>>>(out, ws, upb, db1, dw2, db2);
  k_finalize<<<1, 256, 0, stream>>>(ws, out);
}

// Round 8
// 3242.702 us; speedup vs baseline: 1.8823x; 1.0745x over previous
//
#include <hip/hip_runtime.h>

// ---------------- workspace layout (floats) ----------------
constexpr size_t OFF_XN  = 0;                      // 512*1024
constexpr size_t OFF_PF  = 524288;                 // 32768*128
constexpr size_t OFF_W2A = OFF_PF  + 4194304;      // [(cc*3+k)*128+d]
constexpr size_t OFF_W1B = OFF_W2A + 49152;
constexpr size_t OFF_W2B = OFF_W1B + 49152;
constexpr size_t OFF_PW  = OFF_W2B + 49152;        // [(c*16+k)*128+d]
constexpr size_t OFF_UPW = OFF_PW  + 262144;       // [(j*128+e)*128+d]
constexpr size_t OFF_W1D = OFF_UPW + 262144;       // [(c*3+k)*64+o]
constexpr size_t OFF_EMT = OFF_W1D + 24576;        // [j*128+d]
constexpr size_t OFF_EN  = OFF_EMT + 131072;       // 1024
constexpr size_t OFF_RP  = OFF_EN  + 1024;         // 8192
constexpr size_t OFF_VP  = OFF_RP  + 8192;         // 4096
constexpr size_t OFF_IND = OFF_VP  + 4096;         // 32768 int
// total ~21.7 MB

#define DI __device__ __forceinline__

// ---------------- prep: weight transposes + embedT + |e|^2 ----------------
__global__ __launch_bounds__(256) void k_prep(
    const float* __restrict__ w2a, const float* __restrict__ w1b, const float* __restrict__ w2b,
    const float* __restrict__ pw,  const float* __restrict__ upw, const float* __restrict__ w1d,
    const float* __restrict__ em,  float* __restrict__ ws)
{
  int tid = blockIdx.x * 256 + threadIdx.x;
  int stride = gridDim.x * 256;
  for (int i = tid; i < 128*128*3; i += stride) {
    int d = i / 384, r = i % 384;          // r = cc*3+k
    ws[OFF_W2A + (size_t)r*128 + d] = w2a[i];
    ws[OFF_W1B + (size_t)r*128 + d] = w1b[i];
    ws[OFF_W2B + (size_t)r*128 + d] = w2b[i];
  }
  for (int i = tid; i < 128*128*16; i += stride) {
    int d = i / 2048, r = i % 2048;        // r = c*16+k
    ws[OFF_PW + (size_t)r*128 + d] = pw[i];
  }
  for (int i = tid; i < 128*128*16; i += stride) {
    int e = i / 2048, rem = i % 2048;
    int d = rem / 16, j = rem % 16;
    ws[OFF_UPW + (size_t)(j*128 + e)*128 + d] = upw[i];
  }
  for (int i = tid; i < 64*128*3; i += stride) {
    int o = i / 384, r = i % 384;          // r = c*3+k
    ws[OFF_W1D + (size_t)r*64 + o] = w1d[i];
  }
  for (int j = tid; j < 1024; j += stride) {
    float s = 0.f;
    for (int d = 0; d < 128; ++d) {
      float v = em[d*1024 + j];
      ws[OFF_EMT + (size_t)j*128 + d] = v;
      s = fmaf(v, v, s);
    }
    ws[OFF_EN + j] = s;
  }
}

// ---------------- RevIN ----------------
__global__ __launch_bounds__(256) void k_revin(
    const float* __restrict__ x, const float* __restrict__ rw, const float* __restrict__ rb,
    float* __restrict__ xn)
{
  int n = blockIdx.x;            // sample = b*8 + c
  int b = n >> 3, c = n & 7;
  int t = threadIdx.x;
  const float* xp = x + (size_t)b*8192 + c;
  float v[4]; float s = 0.f, s2 = 0.f;
  #pragma unroll
  for (int i = 0; i < 4; ++i) {
    v[i] = xp[(size_t)(t + i*256)*8];
    s += v[i]; s2 = fmaf(v[i], v[i], s2);
  }
  __shared__ float sh[8];
  __shared__ float st[2];
  for (int o = 32; o; o >>= 1) { s += __shfl_down(s, o, 64); s2 += __shfl_down(s2, o, 64); }
  if ((t & 63) == 0) { sh[t >> 6] = s; sh[4 + (t >> 6)] = s2; }
  __syncthreads();
  if (t == 0) {
    float S = sh[0]+sh[1]+sh[2]+sh[3];
    float S2 = sh[4]+sh[5]+sh[6]+sh[7];
    float mu = S * (1.f/1024.f);
    float var = S2 * (1.f/1024.f) - mu*mu;
    st[0] = mu;
    st[1] = 1.f / sqrtf(var + 1e-5f);
  }
  __syncthreads();
  float mu = st[0], inv = st[1], w0 = rw[0], b0 = rb[0];
  #pragma unroll
  for (int i = 0; i < 4; ++i)
    xn[(size_t)n*1024 + t + i*256] = fmaf((v[i]-mu)*inv, w0, b0);
}

// ---------------- fully fused encoder (unchanged from R7, verified) ----------------
constexpr int STA = 70;
constexpr int STB = 68;

__global__ __launch_bounds__(512) void k_enc(
    const float* __restrict__ xn, float* __restrict__ pf,
    const float* __restrict__ w1a, const float* __restrict__ b1a,
    const float* __restrict__ w2aT, const float* __restrict__ b2a,
    const float* __restrict__ wd,  const float* __restrict__ bd,
    const float* __restrict__ w1bT, const float* __restrict__ b1b,
    const float* __restrict__ w2bT, const float* __restrict__ b2b,
    const float* __restrict__ pwT, const float* __restrict__ pb)
{
  __shared__ float xs[72];
  __shared__ __align__(16) float bufA[64*STA];
  __shared__ __align__(16) float bufB[128*STB];
  int n = blockIdx.x >> 4, tile = blockIdx.x & 15;
  int l0 = tile * 64;
  int t = threadIdx.x;
  int lane = t & 63;
  int w = __builtin_amdgcn_readfirstlane(t >> 6);
  int d0 = w * 16;

  if (t < 72) {
    int gl = l0 - 8 + t;
    xs[t] = (gl >= 0) ? xn[(size_t)n*1024 + gl] : 0.f;
  }
  __syncthreads();

  float acc2[16];
  #pragma unroll
  for (int i = 0; i < 16; ++i) acc2[i] = 0.f;
  float hacc[4] = {0.f, 0.f, 0.f, 0.f};

  for (int rep = 0; rep < 2; ++rep) {
    {
      int row = t & 63, colg = t >> 6;
      int c = rep*64 + row;
      float w0 = w1a[c*3+0], w1 = w1a[c*3+1], w2 = w1a[c*3+2], bb = b1a[c];
      #pragma unroll
      for (int i = 0; i < 9; ++i) {
        int j = colg*9 + i;
        if (j < 70) {
          float v = fmaf(w0, xs[j], fmaf(w1, xs[j+1], fmaf(w2, xs[j+2], bb)));
          bufA[row*STA + j] = (l0 - 6 + j >= 0) ? fmaxf(v, 0.f) : 0.f;
        }
      }
    }
    __syncthreads();
    for (int cc2 = 0; cc2 < 64; ++cc2) {
      float r0 = bufA[cc2*STA + lane + 4];
      float r1 = bufA[cc2*STA + lane + 5];
      float r2 = bufA[cc2*STA + lane + 6];
      const float4* wp = (const float4*)(w2aT + (size_t)(rep*64 + cc2)*384 + d0);
      #pragma unroll
      for (int jj = 0; jj < 4; ++jj) {
        float4 a = wp[jj], b = wp[32+jj], c4 = wp[64+jj];
        acc2[jj*4+0] = fmaf(a.x, r0, fmaf(b.x, r1, fmaf(c4.x, r2, acc2[jj*4+0])));
        acc2[jj*4+1] = fmaf(a.y, r0, fmaf(b.y, r1, fmaf(c4.y, r2, acc2[jj*4+1])));
        acc2[jj*4+2] = fmaf(a.z, r0, fmaf(b.z, r1, fmaf(c4.z, r2, acc2[jj*4+2])));
        acc2[jj*4+3] = fmaf(a.w, r0, fmaf(b.w, r1, fmaf(c4.w, r2, acc2[jj*4+3])));
      }
    }
    if (t < 128) {
      for (int cc2 = 0; cc2 < 64; ++cc2) {
        const float* wp = w2aT + (size_t)(rep*64 + cc2)*384 + t;
        float w0 = wp[0], w1 = wp[128], w2 = wp[256];
        float q0 = bufA[cc2*STA+0], q1 = bufA[cc2*STA+1], q2 = bufA[cc2*STA+2],
              q3 = bufA[cc2*STA+3], q4 = bufA[cc2*STA+4], q5 = bufA[cc2*STA+5];
        hacc[0] = fmaf(w0, q0, fmaf(w1, q1, fmaf(w2, q2, hacc[0])));
        hacc[1] = fmaf(w0, q1, fmaf(w1, q2, fmaf(w2, q3, hacc[1])));
        hacc[2] = fmaf(w0, q2, fmaf(w1, q3, fmaf(w2, q4, hacc[2])));
        hacc[3] = fmaf(w0, q3, fmaf(w1, q4, fmaf(w2, q5, hacc[3])));
      }
    }
    __syncthreads();
  }

  {
    float xv = xs[lane + 8];
    #pragma unroll
    for (int i = 0; i < 16; ++i) {
      int d = d0 + i;
      bufB[d*STB + lane + 4] =
        fmaxf(fmaxf(acc2[i] + b2a[d], 0.f) + fmaf(wd[d], xv, bd[d]), 0.f);
    }
    if (t < 128) {
      #pragma unroll
      for (int h = 0; h < 4; ++h) {
        int l = l0 - 4 + h;
        float o = 0.f;
        if (l >= 0)
          o = fmaxf(fmaxf(hacc[h] + b2a[t], 0.f) + fmaf(wd[t], xs[h+4], bd[t]), 0.f);
        bufB[t*STB + h] = o;
      }
    }
  }
  __syncthreads();

  float acc4[16];
  #pragma unroll
  for (int i = 0; i < 16; ++i) acc4[i] = 0.f;
  for (int rep = 0; rep < 2; ++rep) {
    {
      float acc3[8];
      #pragma unroll
      for (int i = 0; i < 8; ++i) acc3[i] = 0.f;
      int dh = rep*64 + w*8;
      for (int cc = 0; cc < 128; ++cc) {
        float r0 = bufB[cc*STB + lane];
        float r1 = bufB[cc*STB + lane + 1];
        float r2 = bufB[cc*STB + lane + 2];
        const float4* wp = (const float4*)(w1bT + (size_t)cc*384 + dh);
        float4 a0 = wp[0],  a1 = wp[1];
        float4 b0 = wp[32], b1 = wp[33];
        float4 c0 = wp[64], c1 = wp[65];
        acc3[0] = fmaf(a0.x, r0, fmaf(b0.x, r1, fmaf(c0.x, r2, acc3[0])));
        acc3[1] = fmaf(a0.y, r0, fmaf(b0.y, r1, fmaf(c0.y, r2, acc3[1])));
        acc3[2] = fmaf(a0.z, r0, fmaf(b0.z, r1, fmaf(c0.z, r2, acc3[2])));
        acc3[3] = fmaf(a0.w, r0, fmaf(b0.w, r1, fmaf(c0.w, r2, acc3[3])));
        acc3[4] = fmaf(a1.x, r0, fmaf(b1.x, r1, fmaf(c1.x, r2, acc3[4])));
        acc3[5] = fmaf(a1.y, r0, fmaf(b1.y, r1, fmaf(c1.y, r2, acc3[5])));
        acc3[6] = fmaf(a1.z, r0, fmaf(b1.z, r1, fmaf(c1.z, r2, acc3[6])));
        acc3[7] = fmaf(a1.w, r0, fmaf(b1.w, r1, fmaf(c1.w, r2, acc3[7])));
      }
      bool valid = (l0 - 2 + lane >= 0);
      #pragma unroll
      for (int i = 0; i < 8; ++i)
        bufA[(w*8+i)*STA + lane] = valid ? fmaxf(acc3[i] + b1b[dh+i], 0.f) : 0.f;
      if (t < 64) {
        int d = rep*64 + t;
        float h0 = 0.f, h1v = 0.f;
        for (int cc = 0; cc < 128; ++cc) {
          const float* wp = w1bT + (size_t)cc*384 + d;
          float w0 = wp[0], w1 = wp[128], w2 = wp[256];
          float q0 = bufB[cc*STB + 64], q1 = bufB[cc*STB + 65],
                q2 = bufB[cc*STB + 66], q3 = bufB[cc*STB + 67];
          h0  = fmaf(w0, q0, fmaf(w1, q1, fmaf(w2, q2, h0)));
          h1v = fmaf(w0, q1, fmaf(w1, q2, fmaf(w2, q3, h1v)));
        }
        bufA[t*STA + 64] = fmaxf(h0  + b1b[d], 0.f);
        bufA[t*STA + 65] = fmaxf(h1v + b1b[d], 0.f);
      }
    }
    __syncthreads();
    for (int row = 0; row < 64; ++row) {
      float r0 = bufA[row*STA + lane];
      float r1 = bufA[row*STA + lane + 1];
      float r2 = bufA[row*STA + lane + 2];
      const float4* wp = (const float4*)(w2bT + (size_t)(rep*64 + row)*384 + d0);
      #pragma unroll
      for (int jj = 0; jj < 4; ++jj) {
        float4 a = wp[jj], b = wp[32+jj], c4 = wp[64+jj];
        acc4[jj*4+0] = fmaf(a.x, r0, fmaf(b.x, r1, fmaf(c4.x, r2, acc4[jj*4+0])));
        acc4[jj*4+1] = fmaf(a.y, r0, fmaf(b.y, r1, fmaf(c4.y, r2, acc4[jj*4+1])));
        acc4[jj*4+2] = fmaf(a.z, r0, fmaf(b.z, r1, fmaf(c4.z, r2, acc4[jj*4+2])));
        acc4[jj*4+3] = fmaf(a.w, r0, fmaf(b.w, r1, fmaf(c4.w, r2, acc4[jj*4+3])));
      }
    }
    __syncthreads();
  }

  {
    float o1[16];
    #pragma unroll
    for (int i = 0; i < 16; ++i) {
      float res = bufB[(d0+i)*STB + lane + 4];
      o1[i] = fmaxf(fmaxf(acc4[i] + b2b[d0+i], 0.f) + res, 0.f);
    }
    __syncthreads();
    #pragma unroll
    for (int i = 0; i < 16; ++i) bufB[(d0+i)*STB + lane] = o1[i];
  }
  __syncthreads();

  {
    int cq = t >> 7, dd = t & 127;
    float accp[4] = {0.f, 0.f, 0.f, 0.f};
    for (int cl = 0; cl < 32; ++cl) {
      int c = cq*32 + cl;
      const float* row = bufB + c*STB;
      const float* wrow = pwT + (size_t)c*2048 + dd;
      float wv[16];
      #pragma unroll
      for (int k = 0; k < 16; ++k) wv[k] = wrow[(size_t)k*128];
      #pragma unroll
      for (int p = 0; p < 4; ++p) {
        float4 a0 = *(const float4*)(row + p*16);
        float4 a1 = *(const float4*)(row + p*16 + 4);
        float4 a2 = *(const float4*)(row + p*16 + 8);
        float4 a3 = *(const float4*)(row + p*16 + 12);
        accp[p] = fmaf(a0.x, wv[0],  accp[p]);
        accp[p] = fmaf(a0.y, wv[1],  accp[p]);
        accp[p] = fmaf(a0.z, wv[2],  accp[p]);
        accp[p] = fmaf(a0.w, wv[3],  accp[p]);
        accp[p] = fmaf(a1.x, wv[4],  accp[p]);
        accp[p] = fmaf(a1.y, wv[5],  accp[p]);
        accp[p] = fmaf(a1.z, wv[6],  accp[p]);
        accp[p] = fmaf(a1.w, wv[7],  accp[p]);
        accp[p] = fmaf(a2.x, wv[8],  accp[p]);
        accp[p] = fmaf(a2.y, wv[9],  accp[p]);
        accp[p] = fmaf(a2.z, wv[10], accp[p]);
        accp[p] = fmaf(a2.w, wv[11], accp[p]);
        accp[p] = fmaf(a3.x, wv[12], accp[p]);
        accp[p] = fmaf(a3.y, wv[13], accp[p]);
        accp[p] = fmaf(a3.z, wv[14], accp[p]);
        accp[p] = fmaf(a3.w, wv[15], accp[p]);
      }
    }
    #pragma unroll
    for (int p = 0; p < 4; ++p) bufA[(cq*4 + p)*128 + dd] = accp[p];
  }
  __syncthreads();
  {
    int p = t >> 7, dd = t & 127;
    float s = bufA[p*128 + dd];
    s += bufA[(4 + p)*128 + dd];
    s += bufA[(8 + p)*128 + dd];
    s += bufA[(12 + p)*128 + dd];
    pf[((size_t)n*64 + tile*4 + p)*128 + dd] = s + pb[dd];
  }
}

// ---------------- VQ argmin: dist' = |e|^2 - 2 f.e ----------------
__global__ __launch_bounds__(256) void k_vq(float* ws)
{
  __shared__ __align__(16) float fT[128*132];
  __shared__ __align__(16) float ech[64*128];
  __shared__ float ens[64];
  __shared__ float2 red[128*16];
  const float* pf  = ws + OFF_PF;
  const float* emT = ws + OFF_EMT;
  const float* en  = ws + OFF_EN;
  int* ind = (int*)(ws + OFF_IND);

  int t = threadIdx.x;
  int r0 = blockIdx.x * 128;
  for (int s = t; s < 16384; s += 256) {
    int rr = s >> 7, d = s & 127;
    fT[d*132 + rr] = pf[(size_t)(r0 + rr)*128 + d];
  }
  int rg = t & 15, jg = t >> 4;
  float bv[8]; int bi[8];
  #pragma unroll
  for (int r = 0; r < 8; ++r) { bv[r] = 3.4e38f; bi[r] = 0; }

  for (int ch = 0; ch < 16; ++ch) {
    __syncthreads();
    {
      const float4* src = (const float4*)(emT + (size_t)ch*8192);
      for (int q = t; q < 2048; q += 256) {
        int jj = q >> 5, dq4 = q & 31;
        *(float4*)(ech + jj*128 + ((dq4*4) ^ ((jj&7)<<2))) = src[q];
      }
      if (t < 64) ens[t] = en[ch*64 + t];
    }
    __syncthreads();
    float acc[8][4] = {};
    for (int db = 0; db < 128; db += 4) {
      float4 e0 = *(const float4*)(ech + (jg*4+0)*128 + (db ^ (((jg*4+0)&7)<<2)));
      float4 e1 = *(const float4*)(ech + (jg*4+1)*128 + (db ^ (((jg*4+1)&7)<<2)));
      float4 e2 = *(const float4*)(ech + (jg*4+2)*128 + (db ^ (((jg*4+2)&7)<<2)));
      float4 e3 = *(const float4*)(ech + (jg*4+3)*128 + (db ^ (((jg*4+3)&7)<<2)));
      #pragma unroll
      for (int u = 0; u < 4; ++u) {
        const float* fp = fT + (db+u)*132 + rg*8;
        float4 fa = *(const float4*)fp;
        float4 fb = *(const float4*)(fp + 4);
        float fv[8] = {fa.x,fa.y,fa.z,fa.w,fb.x,fb.y,fb.z,fb.w};
        float ev[4] = { ((const float*)&e0)[u], ((const float*)&e1)[u],
                        ((const float*)&e2)[u], ((const float*)&e3)[u] };
        #pragma unroll
        for (int r = 0; r < 8; ++r)
          #pragma unroll
          for (int j = 0; j < 4; ++j)
            acc[r][j] = fmaf(fv[r], ev[j], acc[r][j]);
      }
    }
    #pragma unroll
    for (int r = 0; r < 8; ++r)
      #pragma unroll
      for (int j = 0; j < 4; ++j) {
        float dist = ens[jg*4 + j] - 2.f*acc[r][j];
        int code = ch*64 + jg*4 + j;
        if (dist < bv[r]) { bv[r] = dist; bi[r] = code; }
      }
  }
  __syncthreads();
  #pragma unroll
  for (int r = 0; r < 8; ++r)
    red[(rg*8 + r)*16 + jg] = make_float2(bv[r], __int_as_float(bi[r]));
  __syncthreads();
  if (t < 128) {
    float2 v0 = red[t*16 + 0];
    float best = v0.x; int besti = __float_as_int(v0.y);
    for (int j = 1; j < 16; ++j) {
      float2 v = red[t*16 + j];
      int vi = __float_as_int(v.y);
      if (v.x < best || (v.x == best && vi < besti)) { best = v.x; besti = vi; }
    }
    ind[r0 + t] = besti;
  }
}

// ---------------- gather: z_q -> d_out, vq-loss partials ----------------
__global__ __launch_bounds__(256) void k_gather(float* ws, float* __restrict__ dout)
{
  const float* pf  = ws + OFF_PF;
  const float* emT = ws + OFF_EMT;
  const int* ind = (const int*)(ws + OFF_IND);
  float* vq_part = ws + OFF_VP;

  int t = threadIdx.x;
  int d = t & 127;
  float s = 0.f;
  #pragma unroll
  for (int it = 0; it < 4; ++it) {
    int rr = (t >> 7) + it*2;
    size_t row = (size_t)blockIdx.x*8 + rr;
    int idx = ind[row];
    float q = emT[(size_t)idx*128 + d];
    float f = pf[row*128 + d];
    float qm = q - f;
    dout[row*128 + d] = f + qm;
    s = fmaf(qm, qm, s);
  }
  __shared__ float sh[4];
  for (int o = 32; o; o >>= 1) s += __shfl_down(s, o, 64);
  if ((t & 63) == 0) sh[t >> 6] = s;
  __syncthreads();
  if (t == 0) vq_part[blockIdx.x] = sh[0]+sh[1]+sh[2]+sh[3];
}

DI float gelu_f(float x) {
  float u = x * fmaf(0.0356774081f, x*x, 0.7978845608f);
  float e = __expf(2.f * u);
  float th = 1.f - 2.f / (e + 1.f);
  return 0.5f * x * (1.f + th);
}

// ---------------- decoder: tile=64, 512 threads; D1 = encoder-style conv ----------------
// D1: wave w -> o-slice o0 = w*8; lane = col (d1 col j <-> l = l0-1+j); halo j=64,65.
__global__ __launch_bounds__(512) void k_decoder(
    const float* __restrict__ zq, float* ws,
    const float* __restrict__ upb, const float* __restrict__ db1,
    const float* __restrict__ dw2, const float* __restrict__ db2)
{
  constexpr int UPS = 70;   // up col j <-> l = l0-2+j, j=0..67 used
  constexpr int DS  = 70;   // d1 col j <-> l = l0-1+j, j=0..65 used
  __shared__ __align__(16) float ztT[128*8];
  __shared__ __align__(16) float up_s[128*UPS];
  __shared__ __align__(16) float dsh[64*DS];
  __shared__ __align__(16) float wd2[200];

  const float* upwT = ws + OFF_UPW;
  const float* w1dT = ws + OFF_W1D;
  const float* xn   = ws + OFF_XN;
  float* recon_part = ws + OFF_RP;

  int blk = blockIdx.x;
  int n = blk >> 4, tile = blk & 15;
  int l0 = tile*64, p0 = tile*4;
  int t = threadIdx.x;
  int lane = t & 63;
  int w = __builtin_amdgcn_readfirstlane(t >> 6);

  for (int s = t; s < 768; s += 512) {
    int e = s & 127, pi = s >> 7;
    int p = p0 - 1 + pi;
    ztT[e*8 + pi] = (p >= 0 && p < 64) ? zq[((size_t)n*64 + p)*128 + e] : 0.f;
  }
  __syncthreads();

  // phase U: thread = (jj = t>>5, d4 = (t&31)*4); float4 weights (unchanged)
  {
    int jj = t >> 5;
    int d4 = (t & 31) * 4;
    float acc[6][4] = {};
    const float* wbase = upwT + (size_t)jj*16384 + d4;
    for (int e = 0; e < 128; ++e) {
      float4 z0 = *(const float4*)(ztT + e*8);
      float2 z1 = *(const float2*)(ztT + e*8 + 4);
      float zr[6] = {z0.x, z0.y, z0.z, z0.w, z1.x, z1.y};
      float4 wv = *(const float4*)(wbase + (size_t)e*128);
      #pragma unroll
      for (int pi = 0; pi < 6; ++pi) {
        acc[pi][0] = fmaf(zr[pi], wv.x, acc[pi][0]);
        acc[pi][1] = fmaf(zr[pi], wv.y, acc[pi][1]);
        acc[pi][2] = fmaf(zr[pi], wv.z, acc[pi][2]);
        acc[pi][3] = fmaf(zr[pi], wv.w, acc[pi][3]);
      }
    }
    float ub0 = upb[d4], ub1 = upb[d4+1], ub2 = upb[d4+2], ub3 = upb[d4+3];
    #pragma unroll
    for (int pi = 0; pi < 6; ++pi) {
      int l = (p0 - 1 + pi)*16 + jj;
      int col = l - l0 + 2;
      if (col >= 0 && col < 68) {
        bool v = ((unsigned)l < 1024u);
        up_s[(d4+0)*UPS + col] = v ? acc[pi][0] + ub0 : 0.f;
        up_s[(d4+1)*UPS + col] = v ? acc[pi][1] + ub1 : 0.f;
        up_s[(d4+2)*UPS + col] = v ? acc[pi][2] + ub2 : 0.f;
        up_s[(d4+3)*UPS + col] = v ? acc[pi][3] + ub3 : 0.f;
      }
    }
  }
  __syncthreads();

  // phase D1 main: d1[o0+i][lane], l = l0-1+lane; up window j = lane..lane+2
  {
    int o0 = w * 8;
    float accd[8];
    #pragma unroll
    for (int i = 0; i < 8; ++i) accd[i] = 0.f;
    for (int c = 0; c < 128; ++c) {
      float r0 = up_s[c*UPS + lane];
      float r1 = up_s[c*UPS + lane + 1];
      float r2 = up_s[c*UPS + lane + 2];
      const float* wb = w1dT + (size_t)c*192 + o0;   // (c*3+k)*64 + o0
      float4 wa0 = *(const float4*)(wb);
      float4 wa1 = *(const float4*)(wb + 4);
      float4 wb0 = *(const float4*)(wb + 64);
      float4 wb1 = *(const float4*)(wb + 68);
      float4 wc0 = *(const float4*)(wb + 128);
      float4 wc1 = *(const float4*)(wb + 132);
      accd[0] = fmaf(wa0.x, r0, fmaf(wb0.x, r1, fmaf(wc0.x, r2, accd[0])));
      accd[1] = fmaf(wa0.y, r0, fmaf(wb0.y, r1, fmaf(wc0.y, r2, accd[1])));
      accd[2] = fmaf(wa0.z, r0, fmaf(wb0.z, r1, fmaf(wc0.z, r2, accd[2])));
      accd[3] = fmaf(wa0.w, r0, fmaf(wb0.w, r1, fmaf(wc0.w, r2, accd[3])));
      accd[4] = fmaf(wa1.x, r0, fmaf(wb1.x, r1, fmaf(wc1.x, r2, accd[4])));
      accd[5] = fmaf(wa1.y, r0, fmaf(wb1.y, r1, fmaf(wc1.y, r2, accd[5])));
      accd[6] = fmaf(wa1.z, r0, fmaf(wb1.z, r1, fmaf(wc1.z, r2, accd[6])));
      accd[7] = fmaf(wa1.w, r0, fmaf(wb1.w, r1, fmaf(wc1.w, r2, accd[7])));
    }
    // halo: cols 64,65 (l = l0+63, l0+64); t<128: o = t&63, hc = 64 + (t>>6)
    float hv = 0.f;
    int ho = t & 63, hc = 64 + (t >> 6);
    if (t < 128) {
      for (int c = 0; c < 128; ++c) {
        float q0 = up_s[c*UPS + hc];
        float q1 = up_s[c*UPS + hc + 1];
        float q2 = up_s[c*UPS + hc + 2];
        const float* wb = w1dT + (size_t)c*192 + ho;
        hv = fmaf(wb[0], q0, fmaf(wb[64], q1, fmaf(wb[128], q2, hv)));
      }
    }
    // store with gelu (dsh is free: no aliasing in this scheme)
    {
      int l = l0 - 1 + lane;
      bool v = ((unsigned)l < 1024u);
      #pragma unroll
      for (int i = 0; i < 8; ++i) {
        float x = accd[i] + db1[o0+i];
        dsh[(o0+i)*DS + lane] = v ? gelu_f(x) : 0.f;
      }
    }
    if (t < 128) {
      int l = l0 - 1 + hc;
      bool v = ((unsigned)l < 1024u);
      float x = hv + db1[ho];
      dsh[ho*DS + hc] = v ? gelu_f(x) : 0.f;
    }
  }
  if (t < 192) wd2[t] = dw2[t];
  __syncthreads();

  // phase D2 + recon partial (unchanged)
  if (t < 256) {
    int loff = t & 63, ch = t >> 6;
    float part = 0.f;
    for (int cl = 0; cl < 16; ++cl) {
      int c = ch*16 + cl;
      part = fmaf(wd2[c*3+0], dsh[c*DS + loff],
             fmaf(wd2[c*3+1], dsh[c*DS + loff + 1],
             fmaf(wd2[c*3+2], dsh[c*DS + loff + 2], part)));
    }
    ztT[loff*4 + ch] = part;
  }
  __syncthreads();
  if (t < 64) {
    float acc = ztT[t*4+0] + ztT[t*4+1] + ztT[t*4+2] + ztT[t*4+3] + db2[0];
    float diff = acc - xn[(size_t)n*1024 + l0 + t];
    float part = diff*diff;
    for (int o = 32; o; o >>= 1) part += __shfl_down(part, o, 64);
    if (t == 0) recon_part[blk] = part;
  }
}

// ---------------- finalize loss ----------------
__global__ __launch_bounds__(256) void k_finalize(const float* __restrict__ ws, float* __restrict__ dout)
{
  const float* rp = ws + OFF_RP;
  const float* vp = ws + OFF_VP;
  int t = threadIdx.x;
  float s1 = 0.f, s2 = 0.f;
  for (int i = t; i < 8192; i += 256) s1 += rp[i];
  for (int i = t; i < 4096; i += 256) s2 += vp[i];
  __shared__ float sh[8];
  for (int o = 32; o; o >>= 1) { s1 += __shfl_down(s1,o,64); s2 += __shfl_down(s2,o,64); }
  if ((t & 63) == 0) { sh[t >> 6] = s1; sh[4 + (t >> 6)] = s2; }
  __syncthreads();
  if (t == 0) {
    float R = sh[0]+sh[1]+sh[2]+sh[3];
    float V = sh[4]+sh[5]+sh[6]+sh[7];
    dout[4194304] = R * (1.f/524288.f) + 0.25f * (V * (1.f/4194304.f));
  }
}

// ---------------- host ----------------
extern "C" void kernel_launch(void* const* d_in, const int* in_sizes, int n_in,
                              void* d_out, int out_size, void* d_ws, size_t ws_size,
                              hipStream_t stream)
{
  const float* x    = (const float*)d_in[0];
  const float* rw   = (const float*)d_in[1];
  const float* rb   = (const float*)d_in[2];
  const float* w1a  = (const float*)d_in[3];
  const float* b1a  = (const float*)d_in[4];
  const float* w2a  = (const float*)d_in[5];
  const float* b2a  = (const float*)d_in[6];
  const float* wda  = (const float*)d_in[7];
  const float* bda  = (const float*)d_in[8];
  const float* w1b  = (const float*)d_in[9];
  const float* b1b  = (const float*)d_in[10];
  const float* w2b  = (const float*)d_in[11];
  const float* b2b  = (const float*)d_in[12];
  const float* pw   = (const float*)d_in[13];
  const float* pb   = (const float*)d_in[14];
  const float* em   = (const float*)d_in[15];
  const float* upw  = (const float*)d_in[16];
  const float* upb  = (const float*)d_in[17];
  const float* dw1  = (const float*)d_in[18];
  const float* db1  = (const float*)d_in[19];
  const float* dw2  = (const float*)d_in[20];
  const float* db2  = (const float*)d_in[21];
  float* ws = (float*)d_ws;
  float* out = (float*)d_out;

  float* xn = ws + OFF_XN;
  float* pf = ws + OFF_PF;
  const float* w2aT = ws + OFF_W2A;
  const float* w1bT = ws + OFF_W1B;
  const float* w2bT = ws + OFF_W2B;
  const float* pwT  = ws + OFF_PW;

  k_prep<<<256, 256, 0, stream>>>(w2a, w1b, w2b, pw, upw, dw1, em, ws);
  k_revin<<<512, 256, 0, stream>>>(x, rw, rb, xn);
  k_enc<<<8192, 512, 0, stream>>>(xn, pf, w1a, b1a, w2aT, b2a, wda, bda,
                                  w1bT, b1b, w2bT, b2b, pwT, pb);
  k_vq<<<256, 256, 0, stream>>>(ws);
  k_gather<<<4096, 256, 0, stream>>>(ws, out);
  k_decoder<<<8192, 512, 0, stream>>>(out, ws, upb, db1, dw2, db2);
  k_finalize<<<1, 256, 0, stream>>>(ws, out);
}